// Round 14
// baseline (316.960 us; speedup 1.0000x reference)
//
#include <hip/hip_runtime.h>
#include <math.h>

#define N_USER 100000
#define N_ITEM 50000
#define N_EDGE 800000
#define D_IN 256
#define D_H 128
#define HEADS 4

typedef __attribute__((ext_vector_type(8))) short short8v;   // 8 bf16 (4 VGPR)
typedef __attribute__((ext_vector_type(4))) float f32x4;     // 4 fp32

__device__ __forceinline__ unsigned short f2bf(float x) {    // RNE f32->bf16
  unsigned u = __float_as_uint(x);
  return (unsigned short)((u + 0x7FFFu + ((u >> 16) & 1u)) >> 16);
}
__device__ __forceinline__ float bf2f(unsigned short h) {
  return __uint_as_float((unsigned)h << 16);
}
__device__ __forceinline__ f32x4 splat4(float x) { return (f32x4){x, x, x, x}; }

// ---------------------------------------------------------------------------
// CSR row offsets, edge-parallel run writes (each rs[i] written exactly once).
// ---------------------------------------------------------------------------
__global__ void row_offsets_kernel(const int* __restrict__ dst, int n_edge,
                                   int* __restrict__ rs, int n_dst) {
  int e = blockIdx.x * blockDim.x + threadIdx.x;
  if (e >= n_edge) return;
  int d = dst[e];
  int dprev = (e == 0) ? -1 : dst[e - 1];
  for (int i = dprev + 1; i <= d; ++i) rs[i] = e;
  if (e == n_edge - 1)
    for (int i = d + 1; i <= n_dst; ++i) rs[i] = n_edge;
}

// ---------------------------------------------------------------------------
// One-time W prep (RNE split): W[256][128] fp32 -> Wt_hi/Wt_lo[128][256] bf16,
// k permuted to MFMA slot order: pos(k) s.t. slot (kb,j) holds
// k = kb*4 + (j&3) + 16*(j>>2).
// ---------------------------------------------------------------------------
__global__ __launch_bounds__(256) void wt_prep_kernel(
    const float* __restrict__ W, unsigned short* __restrict__ WtHi,
    unsigned short* __restrict__ WtLo) {
  int tid = blockIdx.x * blockDim.x + threadIdx.x;
  if (tid >= D_IN * D_H) return;
  int n = tid & 127, k = tid >> 7;
  float x = W[(size_t)k * D_H + n];
  unsigned short h = f2bf(x);
  unsigned short l = f2bf(x - bf2f(h));
  int kk = k & 31, kbase = k & ~31;
  int pos = (kk < 16) ? ((kk >> 2) * 8 + (kk & 3))
                      : (((kk - 16) >> 2) * 8 + 4 + (kk & 3));
  WtHi[(size_t)n * D_IN + kbase + pos] = h;
  WtLo[(size_t)n * D_IN + kbase + pos] = l;
}

// ---------------------------------------------------------------------------
// Stage one K-step tile (A fp32 64x32 swizzled + B hi/lo 128x32 bf16) into
// LDS entirely via global_load_lds DMA.
// ---------------------------------------------------------------------------
__device__ __forceinline__ void stage_tile(
    const float* __restrict__ A, const unsigned short* __restrict__ WtHi,
    const unsigned short* __restrict__ WtLo, int m0, int M, int k0,
    int wave, int lane, float* Af, unsigned short* Bh, unsigned short* Bl) {
  // A: wave fills rows wave*16..+15 (M-tile 64); lane l -> row base+(l>>3),
  // unit l&7. Source pre-swizzled: unit_src = (lane&7) ^ (row&7) (m104/m173).
#pragma unroll
  for (int i = 0; i < 2; ++i) {
    int rloc = wave * 16 + i * 8 + (lane >> 3);
    int gr = m0 + rloc; if (gr >= M) gr = M - 1;       // clamp; rows never stored
    int u = (lane & 7) ^ (rloc & 7);
    const float* src = A + (size_t)gr * D_IN + k0 + u * 4;
    char* dstb = (char*)Af + (size_t)(wave * 16 + i * 8) * 128;  // wave-uniform
    __builtin_amdgcn_global_load_lds(
        (const __attribute__((address_space(1))) unsigned int*)src,
        (__attribute__((address_space(3))) unsigned int*)dstb, 16, 0, 0);
  }
  // B: row stride 64B; lane l -> row base+(l>>2), 16B unit l&3 (linear).
#pragma unroll
  for (int i = 0; i < 2; ++i) {
    int row = wave * 32 + i * 16 + (lane >> 2);
    int ch = lane & 3;
    const unsigned short* srch = WtHi + (size_t)row * D_IN + k0 + ch * 8;
    char* dsth = (char*)Bh + (size_t)(wave * 32 + i * 16) * 64;
    __builtin_amdgcn_global_load_lds(
        (const __attribute__((address_space(1))) unsigned int*)srch,
        (__attribute__((address_space(3))) unsigned int*)dsth, 16, 0, 0);
    const unsigned short* srcl = WtLo + (size_t)row * D_IN + k0 + ch * 8;
    char* dstl = (char*)Bl + (size_t)(wave * 32 + i * 16) * 64;
    __builtin_amdgcn_global_load_lds(
        (const __attribute__((address_space(1))) unsigned int*)srcl,
        (__attribute__((address_space(3))) unsigned int*)dstl, 16, 0, 0);
  }
}

// ---------------------------------------------------------------------------
// FUSED projections, 2-phase double-buffered, M-TILE 64 (LDS diet 64->48KB:
// r13 measured 18.8% occupancy = 2 blocks/CU gated by 64KB LDS; 48KB -> 3
// blocks/CU = 12 waves/CU, +50% latency-hiding waves; grid 2345 blocks).
// Wave owns 16 rows x 128 cols (acc[8] = 32 VGPR). Operand path (DMA->LDS->
// ds_read) identical to r12/r13 (measured best).
// C/D layout (verified m89): col = lane&15, row = (lane>>4)*4 + reg.
// ---------------------------------------------------------------------------
__global__ __launch_bounds__(256) void gemm_fused_kernel(
    const float* __restrict__ Au, const float* __restrict__ Ai,
    const unsigned short* __restrict__ WtUHi, const unsigned short* __restrict__ WtULo,
    const unsigned short* __restrict__ WtIHi, const unsigned short* __restrict__ WtILo,
    const float* __restrict__ bu, const float* __restrict__ bi,
    float* __restrict__ Cu, float* __restrict__ Ci, int nbu) {
  __shared__ float Af[2][64 * 32];                      // 2 x 8KB
  __shared__ unsigned short Bhs[2][128 * 32];           // 2 x 8KB
  __shared__ unsigned short Bls[2][128 * 32];           // 2 x 8KB  (total 48KB)
  const bool isU = (int)blockIdx.x < nbu;
  const float* A = isU ? Au : Ai;
  const unsigned short* WtHi = isU ? WtUHi : WtIHi;
  const unsigned short* WtLo = isU ? WtULo : WtILo;
  const float* bias = isU ? bu : bi;
  float* C = isU ? Cu : Ci;
  const int M = isU ? N_USER : N_ITEM;
  const int m0 = (isU ? (int)blockIdx.x : (int)blockIdx.x - nbu) * 64;

  const int t = threadIdx.x;
  const int wave = t >> 6, lane = t & 63;
  const int l15 = lane & 15, kb = lane >> 4;

  f32x4 acc[8];
#pragma unroll
  for (int nf = 0; nf < 8; ++nf) acc[nf] = (f32x4){0.f, 0.f, 0.f, 0.f};

  stage_tile(A, WtHi, WtLo, m0, M, 0, wave, lane, Af[0], Bhs[0], Bls[0]);
  __syncthreads();                                     // tile 0 ready

#pragma unroll
  for (int ts = 0; ts < 8; ++ts) {
    const int cur = ts & 1;
    if (ts + 1 < 8)                                    // prefetch next tile
      stage_tile(A, WtHi, WtLo, m0, M, (ts + 1) * 32, wave, lane,
                 Af[cur ^ 1], Bhs[cur ^ 1], Bls[cur ^ 1]);

    // ---- A fragment: ds_read fp32 (swizzled) -> split to bf16 hi/lo ----
    short8v ah, al;
    {
      int row = wave * 16 + l15;
      int u0 = kb ^ (row & 7);                  // slots j=0..3: k = kb*4+j
      int u1 = (kb + 4) ^ (row & 7);            // slots j=4..7: k = 16+kb*4+j-4
      float4 f0 = *(const float4*)((const char*)Af[cur] + (size_t)row * 128 + u0 * 16);
      float4 f1 = *(const float4*)((const char*)Af[cur] + (size_t)row * 128 + u1 * 16);
      const float e[8] = {f0.x, f0.y, f0.z, f0.w, f1.x, f1.y, f1.z, f1.w};
#pragma unroll
      for (int j = 0; j < 8; ++j) {
        unsigned short h = f2bf(e[j]);
        ah[j] = (short)h;
        al[j] = (short)f2bf(e[j] - bf2f(h));
      }
    }
#pragma unroll
    for (int nf = 0; nf < 8; ++nf) {
      short8v bh = *(const short8v*)((const char*)Bhs[cur] + (size_t)(nf * 16 + l15) * 64 + kb * 16);
      short8v bl = *(const short8v*)((const char*)Bls[cur] + (size_t)(nf * 16 + l15) * 64 + kb * 16);
      acc[nf] = __builtin_amdgcn_mfma_f32_16x16x32_bf16(ah, bh, acc[nf], 0, 0, 0);
      acc[nf] = __builtin_amdgcn_mfma_f32_16x16x32_bf16(ah, bl, acc[nf], 0, 0, 0);
      acc[nf] = __builtin_amdgcn_mfma_f32_16x16x32_bf16(al, bh, acc[nf], 0, 0, 0);
    }
    __syncthreads();   // drains this iter's DMA (next tile) + all LDS reads
  }

#pragma unroll
  for (int nf = 0; nf < 8; ++nf) {
    float bv = bias[nf * 16 + l15];
#pragma unroll
    for (int r = 0; r < 4; ++r) {
      int grow = m0 + wave * 16 + kb * 4 + r;
      if (grow < M) C[(size_t)grow * D_H + nf * 16 + l15] = acc[nf][r] + bv;
    }
  }
}

// ---------------------------------------------------------------------------
// s[n,4] = C[n,128] @ a[4,128]^T  (one wave per row; optional second a)
// ---------------------------------------------------------------------------
__global__ __launch_bounds__(256) void scores_kernel(
    const float* __restrict__ C, int n,
    const float* __restrict__ a0, float* __restrict__ s0,
    const float* __restrict__ a1, float* __restrict__ s1) {
  int wid = (blockIdx.x * blockDim.x + threadIdx.x) >> 6;
  int lane = threadIdx.x & 63;
  if (wid >= n) return;
  float2 v = *(const float2*)&C[(size_t)wid * D_H + lane * 2];
#pragma unroll
  for (int h = 0; h < HEADS; ++h) {
    float p = v.x * a0[h * D_H + lane * 2] + v.y * a0[h * D_H + lane * 2 + 1];
#pragma unroll
    for (int off = 32; off; off >>= 1) p += __shfl_xor(p, off);
    if (lane == 0) s0[wid * HEADS + h] = p;
  }
  if (a1) {
#pragma unroll
    for (int h = 0; h < HEADS; ++h) {
      float p = v.x * a1[h * D_H + lane * 2] + v.y * a1[h * D_H + lane * 2 + 1];
#pragma unroll
      for (int off = 32; off; off >>= 1) p += __shfl_xor(p, off);
      if (lane == 0) s1[wid * HEADS + h] = p;
    }
  }
}

// ---------------------------------------------------------------------------
// Per-edge UNNORMALIZED weights w = exp(leaky_relu(s_src+s_dst)).
// ---------------------------------------------------------------------------
__global__ __launch_bounds__(256) void edge_w_kernel(
    const float* __restrict__ s_src, const float* __restrict__ s_dst,
    const int* __restrict__ src_idx, const int* __restrict__ dst_idx,
    float* __restrict__ wout, int n_edge) {
  int e = blockIdx.x * blockDim.x + threadIdx.x;
  if (e >= n_edge) return;
  int s = src_idx[e], d = dst_idx[e];
  f32x4 a = *(const f32x4*)&s_src[(size_t)s * HEADS];
  f32x4 b = *(const f32x4*)&s_dst[(size_t)d * HEADS];
  f32x4 v = a + b;
  v.x = (v.x >= 0.f) ? v.x : 0.2f * v.x;
  v.y = (v.y >= 0.f) ? v.y : 0.2f * v.y;
  v.z = (v.z >= 0.f) ? v.z : 0.2f * v.z;
  v.w = (v.w >= 0.f) ? v.w : 0.2f * v.w;
  f32x4 w = {__expf(v.x), __expf(v.y), __expf(v.z), __expf(v.w)};
  *(f32x4*)&wout[(size_t)e * HEADS] = w;
}

// ---------------------------------------------------------------------------
// Weighted gather-sum + in-loop denominator. One wave per dst;
// lanes = 2 edge-slots x 32 dim-groups (float4). Packed f32x4 math.
// Epilogue: rcp (not div); ELU split across half-waves.
// ---------------------------------------------------------------------------
__global__ __launch_bounds__(256) void attend_sum_kernel(
    const float* __restrict__ h_src, const float* __restrict__ w4,
    const int* __restrict__ src_idx, const int* __restrict__ rs,
    float* __restrict__ out, int n_dst,
    const float* __restrict__ a_next, float* __restrict__ s_out) {
  int wid = (blockIdx.x * blockDim.x + threadIdx.x) >> 6;
  int lane = threadIdx.x & 63;
  if (wid >= n_dst) return;
  const int el = lane >> 5;
  const int dl = lane & 31;
  int e0 = rs[wid], e1 = rs[wid + 1];

  f32x4 acc0 = {0, 0, 0, 0}, acc1 = acc0, acc2 = acc0, acc3 = acc0;
  f32x4 den = {0, 0, 0, 0};

  int base = e0;
  for (; base + 4 <= e1; base += 4) {
    int eA = base + el, eB = base + 2 + el;
    int sA = src_idx[eA], sB = src_idx[eB];
    f32x4 hA = *(const f32x4*)&h_src[(size_t)sA * D_H + dl * 4];
    f32x4 hB = *(const f32x4*)&h_src[(size_t)sB * D_H + dl * 4];
    f32x4 wA = *(const f32x4*)&w4[(size_t)eA * HEADS];
    f32x4 wB = *(const f32x4*)&w4[(size_t)eB * HEADS];
    den += wA; den += wB;
    acc0 = __builtin_elementwise_fma(splat4(wA.x), hA, acc0);
    acc1 = __builtin_elementwise_fma(splat4(wA.y), hA, acc1);
    acc2 = __builtin_elementwise_fma(splat4(wA.z), hA, acc2);
    acc3 = __builtin_elementwise_fma(splat4(wA.w), hA, acc3);
    acc0 = __builtin_elementwise_fma(splat4(wB.x), hB, acc0);
    acc1 = __builtin_elementwise_fma(splat4(wB.y), hB, acc1);
    acc2 = __builtin_elementwise_fma(splat4(wB.z), hB, acc2);
    acc3 = __builtin_elementwise_fma(splat4(wB.w), hB, acc3);
  }
  for (; base < e1; base += 2) {
    int e = base + el;
    bool valid = e < e1;
    int ec = valid ? e : e1 - 1;
    int s = src_idx[ec];
    f32x4 hv = *(const f32x4*)&h_src[(size_t)s * D_H + dl * 4];
    f32x4 wv = *(const f32x4*)&w4[(size_t)ec * HEADS];
    if (!valid) wv = (f32x4){0, 0, 0, 0};
    den += wv;
    acc0 = __builtin_elementwise_fma(splat4(wv.x), hv, acc0);
    acc1 = __builtin_elementwise_fma(splat4(wv.y), hv, acc1);
    acc2 = __builtin_elementwise_fma(splat4(wv.z), hv, acc2);
    acc3 = __builtin_elementwise_fma(splat4(wv.w), hv, acc3);
  }

#define MRG(a) \
  a.x += __shfl_xor(a.x, 32); a.y += __shfl_xor(a.y, 32); \
  a.z += __shfl_xor(a.z, 32); a.w += __shfl_xor(a.w, 32);
  MRG(acc0) MRG(acc1) MRG(acc2) MRG(acc3) MRG(den)
#undef MRG

  float rA = den.x > 0.f ? __builtin_amdgcn_rcpf(den.x) : 0.f;
  float rB = den.y > 0.f ? __builtin_amdgcn_rcpf(den.y) : 0.f;
  float rC = den.z > 0.f ? __builtin_amdgcn_rcpf(den.z) : 0.f;
  float rD = den.w > 0.f ? __builtin_amdgcn_rcpf(den.w) : 0.f;

  f32x4 p = el ? acc2 : acc0;
  f32x4 q = el ? acc3 : acc1;
  float rp = el ? rC : rA;
  float rq = el ? rD : rB;
  p *= splat4(rp); q *= splat4(rq);
#define ELU4(a) \
  a.x = (a.x > 0.f) ? a.x : (__expf(a.x) - 1.f); \
  a.y = (a.y > 0.f) ? a.y : (__expf(a.y) - 1.f); \
  a.z = (a.z > 0.f) ? a.z : (__expf(a.z) - 1.f); \
  a.w = (a.w > 0.f) ? a.w : (__expf(a.w) - 1.f);
  ELU4(p) ELU4(q)
#undef ELU4
  f32x4 s4 = p + q;
  s4.x += __shfl_xor(s4.x, 32);
  s4.y += __shfl_xor(s4.y, 32);
  s4.z += __shfl_xor(s4.z, 32);
  s4.w += __shfl_xor(s4.w, 32);
  f32x4 o = s4 * splat4(0.25f);

  if (el == 0) *(f32x4*)&out[(size_t)wid * D_H + dl * 4] = o;

  if (s_out) {
#pragma unroll
    for (int h = 0; h < HEADS; ++h) {
      const float* ah = &a_next[h * D_H + dl * 4];
      float p2 = o.x * ah[0] + o.y * ah[1] + o.z * ah[2] + o.w * ah[3];
#pragma unroll
      for (int off = 16; off; off >>= 1) p2 += __shfl_xor(p2, off);
      if (lane == 0) s_out[wid * HEADS + h] = p2;
    }
  }
}

// ---------------------------------------------------------------------------
extern "C" void kernel_launch(void* const* d_in, const int* in_sizes, int n_in,
                              void* d_out, int out_size, void* d_ws, size_t ws_size,
                              hipStream_t stream) {
  const float* h_user     = (const float*)d_in[0];
  const float* h_item     = (const float*)d_in[1];
  const float* w_user     = (const float*)d_in[2];
  const float* b_user     = (const float*)d_in[3];
  const float* w_item     = (const float*)d_in[4];
  const float* b_item     = (const float*)d_in[5];
  const float* a_user_src = (const float*)d_in[6];
  const float* a_user_dst = (const float*)d_in[7];
  const float* a_item_src = (const float*)d_in[8];
  const float* a_item_dst = (const float*)d_in[9];
  const int* i2u_src = (const int*)d_in[10];
  const int* i2u_dst = (const int*)d_in[11];
  const int* u2i_src = (const int*)d_in[12];
  const int* u2i_dst = (const int*)d_in[13];

  float* out_user = (float*)d_out;                       // hu_new (N_USER,128)
  float* out_item = out_user + (size_t)N_USER * D_H;     // hi_new (N_ITEM,128)

  // workspace layout
  float* hu      = (float*)d_ws;                         // (N_USER,128) 51.2MB
  float* hi      = hu + (size_t)N_USER * D_H;            // (N_ITEM,128)
  float* s_i_src = hi + (size_t)N_ITEM * D_H;            // (N_ITEM,4)
  float* s_i_dst = s_i_src + (size_t)N_ITEM * HEADS;     // (N_ITEM,4)
  float* s_u_dst = s_i_dst + (size_t)N_ITEM * HEADS;     // (N_USER,4)
  float* s_un    = s_u_dst + (size_t)N_USER * HEADS;     // (N_USER,4)
  int* user_rs = (int*)(s_un + (size_t)N_USER * HEADS);  // N_USER+1
  int* item_rs = user_rs + (N_USER + 1);                 // N_ITEM+1
  unsigned short* wtu_hi = (unsigned short*)
      (((uintptr_t)(item_rs + N_ITEM + 1) + 15) & ~(uintptr_t)15);
  unsigned short* wtu_lo = wtu_hi + (size_t)D_IN * D_H;
  unsigned short* wti_hi = wtu_lo + (size_t)D_IN * D_H;
  unsigned short* wti_lo = wti_hi + (size_t)D_IN * D_H;
  // hu is dead after scores_kernel -> alias edge weight buffer into it
  float* wbuf = hu;                                      // (E,4) 12.8MB

  // CSR offsets (edge-parallel run writes)
  hipLaunchKernelGGL(row_offsets_kernel, dim3((N_EDGE + 255) / 256), dim3(256), 0,
                     stream, i2u_dst, N_EDGE, user_rs, N_USER);
  hipLaunchKernelGGL(row_offsets_kernel, dim3((N_EDGE + 255) / 256), dim3(256), 0,
                     stream, u2i_dst, N_EDGE, item_rs, N_ITEM);

  // W prep + FUSED projections (M64 2-phase dbuf, one dispatch, 2345 blocks)
  hipLaunchKernelGGL(wt_prep_kernel, dim3(D_IN * D_H / 256), dim3(256), 0, stream,
                     w_user, wtu_hi, wtu_lo);
  hipLaunchKernelGGL(wt_prep_kernel, dim3(D_IN * D_H / 256), dim3(256), 0, stream,
                     w_item, wti_hi, wti_lo);
  const int nbu = (N_USER + 63) / 64;                    // 1563
  const int nbi = (N_ITEM + 63) / 64;                    // 782
  hipLaunchKernelGGL(gemm_fused_kernel, dim3(nbu + nbi), dim3(256), 0, stream,
                     h_user, h_item, wtu_hi, wtu_lo, wti_hi, wti_lo,
                     b_user, b_item, hu, hi, nbu);

  // per-node attention scores
  hipLaunchKernelGGL(scores_kernel, dim3(N_ITEM / 4), dim3(256), 0, stream,
                     hi, N_ITEM, a_user_src, s_i_src, a_item_dst, s_i_dst);
  hipLaunchKernelGGL(scores_kernel, dim3(N_USER / 4), dim3(256), 0, stream,
                     hu, N_USER, a_user_dst, s_u_dst, (const float*)nullptr, (float*)nullptr);

  // ---- layer 1: items -> users ----
  hipLaunchKernelGGL(edge_w_kernel, dim3((N_EDGE + 255) / 256), dim3(256), 0, stream,
                     s_i_src, s_u_dst, i2u_src, i2u_dst, wbuf, N_EDGE);
  hipLaunchKernelGGL(attend_sum_kernel, dim3((N_USER + 3) / 4), dim3(256), 0, stream,
                     hi, wbuf, i2u_src, user_rs, out_user, N_USER,
                     a_item_src, s_un);

  // ---- layer 2: updated users -> items ----
  hipLaunchKernelGGL(edge_w_kernel, dim3((N_EDGE + 255) / 256), dim3(256), 0, stream,
                     s_un, s_i_dst, u2i_src, u2i_dst, wbuf, N_EDGE);
  hipLaunchKernelGGL(attend_sum_kernel, dim3((N_ITEM + 3) / 4), dim3(256), 0, stream,
                     out_user, wbuf, u2i_src, item_rs, out_item, N_ITEM,
                     (const float*)nullptr, (float*)nullptr);
}

// Round 15
// 303.469 us; speedup vs baseline: 1.0445x; 1.0445x over previous
//
#include <hip/hip_runtime.h>
#include <math.h>

#define N_USER 100000
#define N_ITEM 50000
#define N_EDGE 800000
#define D_IN 256
#define D_H 128
#define HEADS 4

typedef __attribute__((ext_vector_type(8))) short short8v;   // 8 bf16 (4 VGPR)
typedef __attribute__((ext_vector_type(4))) float f32x4;     // 4 fp32

__device__ __forceinline__ unsigned short f2bf(float x) {    // RNE f32->bf16
  unsigned u = __float_as_uint(x);
  return (unsigned short)((u + 0x7FFFu + ((u >> 16) & 1u)) >> 16);
}
__device__ __forceinline__ float bf2f(unsigned short h) {
  return __uint_as_float((unsigned)h << 16);
}
__device__ __forceinline__ f32x4 splat4(float x) { return (f32x4){x, x, x, x}; }

// ---------------------------------------------------------------------------
// CSR row offsets, edge-parallel run writes (each rs[i] written exactly once).
// ---------------------------------------------------------------------------
__global__ void row_offsets_kernel(const int* __restrict__ dst, int n_edge,
                                   int* __restrict__ rs, int n_dst) {
  int e = blockIdx.x * blockDim.x + threadIdx.x;
  if (e >= n_edge) return;
  int d = dst[e];
  int dprev = (e == 0) ? -1 : dst[e - 1];
  for (int i = dprev + 1; i <= d; ++i) rs[i] = e;
  if (e == n_edge - 1)
    for (int i = d + 1; i <= n_dst; ++i) rs[i] = n_edge;
}

// ---------------------------------------------------------------------------
// One-time W prep (RNE split): W[256][128] fp32 -> Wt_hi/Wt_lo[128][256] bf16,
// k permuted to MFMA slot order: pos(k) s.t. slot (kb,j) holds
// k = kb*4 + (j&3) + 16*(j>>2).
// ---------------------------------------------------------------------------
__global__ __launch_bounds__(256) void wt_prep_kernel(
    const float* __restrict__ W, unsigned short* __restrict__ WtHi,
    unsigned short* __restrict__ WtLo) {
  int tid = blockIdx.x * blockDim.x + threadIdx.x;
  if (tid >= D_IN * D_H) return;
  int n = tid & 127, k = tid >> 7;
  float x = W[(size_t)k * D_H + n];
  unsigned short h = f2bf(x);
  unsigned short l = f2bf(x - bf2f(h));
  int kk = k & 31, kbase = k & ~31;
  int pos = (kk < 16) ? ((kk >> 2) * 8 + (kk & 3))
                      : (((kk - 16) >> 2) * 8 + 4 + (kk & 3));
  WtHi[(size_t)n * D_IN + kbase + pos] = h;
  WtLo[(size_t)n * D_IN + kbase + pos] = l;
}

// ---------------------------------------------------------------------------
// Stage one K-step tile (A fp32 128x32 swizzled + B hi/lo 128x32 bf16) into
// LDS entirely via global_load_lds DMA (r13 measured-best structure).
// ---------------------------------------------------------------------------
__device__ __forceinline__ void stage_tile(
    const float* __restrict__ A, const unsigned short* __restrict__ WtHi,
    const unsigned short* __restrict__ WtLo, int m0, int M, int k0,
    int wave, int lane, float* Af, unsigned short* Bh, unsigned short* Bl) {
  // A: wave fills rows wave*32..+31; lane l -> row base+(l>>3), unit l&7.
  // Source pre-swizzled: unit_src = (lane&7) ^ (row&7)  (m104/m173).
#pragma unroll
  for (int i = 0; i < 4; ++i) {
    int rloc = wave * 32 + i * 8 + (lane >> 3);
    int gr = m0 + rloc; if (gr >= M) gr = M - 1;       // clamp; rows never stored
    int u = (lane & 7) ^ (rloc & 7);
    const float* src = A + (size_t)gr * D_IN + k0 + u * 4;
    char* dstb = (char*)Af + (size_t)(wave * 32 + i * 8) * 128;  // wave-uniform
    __builtin_amdgcn_global_load_lds(
        (const __attribute__((address_space(1))) unsigned int*)src,
        (__attribute__((address_space(3))) unsigned int*)dstb, 16, 0, 0);
  }
  // B: row stride 64B; lane l -> row base+(l>>2), 16B unit l&3 (linear).
#pragma unroll
  for (int i = 0; i < 2; ++i) {
    int row = wave * 32 + i * 16 + (lane >> 2);
    int ch = lane & 3;
    const unsigned short* srch = WtHi + (size_t)row * D_IN + k0 + ch * 8;
    char* dsth = (char*)Bh + (size_t)(wave * 32 + i * 16) * 64;
    __builtin_amdgcn_global_load_lds(
        (const __attribute__((address_space(1))) unsigned int*)srch,
        (__attribute__((address_space(3))) unsigned int*)dsth, 16, 0, 0);
    const unsigned short* srcl = WtLo + (size_t)row * D_IN + k0 + ch * 8;
    char* dstl = (char*)Bl + (size_t)(wave * 32 + i * 16) * 64;
    __builtin_amdgcn_global_load_lds(
        (const __attribute__((address_space(1))) unsigned int*)srcl,
        (__attribute__((address_space(3))) unsigned int*)dstl, 16, 0, 0);
  }
}

// ---------------------------------------------------------------------------
// FUSED projections — EXACT r13 kernel (measured best: 96-103us, total 311.6).
// 2-phase double-buffered, M-tile 128, all staging via global_load_lds DMA.
// C/D layout (verified m89): col = lane&15, row = (lane>>4)*4 + reg.
// ---------------------------------------------------------------------------
__global__ __launch_bounds__(256) void gemm_fused_kernel(
    const float* __restrict__ Au, const float* __restrict__ Ai,
    const unsigned short* __restrict__ WtUHi, const unsigned short* __restrict__ WtULo,
    const unsigned short* __restrict__ WtIHi, const unsigned short* __restrict__ WtILo,
    const float* __restrict__ bu, const float* __restrict__ bi,
    float* __restrict__ Cu, float* __restrict__ Ci, int nbu) {
  __shared__ float Af[2][128 * 32];                     // 2 x 16KB
  __shared__ unsigned short Bhs[2][128 * 32];           // 2 x 8KB
  __shared__ unsigned short Bls[2][128 * 32];           // 2 x 8KB  (total 64KB)
  const bool isU = (int)blockIdx.x < nbu;
  const float* A = isU ? Au : Ai;
  const unsigned short* WtHi = isU ? WtUHi : WtIHi;
  const unsigned short* WtLo = isU ? WtULo : WtILo;
  const float* bias = isU ? bu : bi;
  float* C = isU ? Cu : Ci;
  const int M = isU ? N_USER : N_ITEM;
  const int m0 = (isU ? (int)blockIdx.x : (int)blockIdx.x - nbu) * 128;

  const int t = threadIdx.x;
  const int wave = t >> 6, lane = t & 63;
  const int l15 = lane & 15, kb = lane >> 4;

  f32x4 acc[2][8];
#pragma unroll
  for (int mf = 0; mf < 2; ++mf)
#pragma unroll
    for (int nf = 0; nf < 8; ++nf) acc[mf][nf] = (f32x4){0.f, 0.f, 0.f, 0.f};

  stage_tile(A, WtHi, WtLo, m0, M, 0, wave, lane, Af[0], Bhs[0], Bls[0]);
  __syncthreads();                                     // tile 0 ready

#pragma unroll
  for (int ts = 0; ts < 8; ++ts) {
    const int cur = ts & 1;
    if (ts + 1 < 8)                                    // prefetch next tile
      stage_tile(A, WtHi, WtLo, m0, M, (ts + 1) * 32, wave, lane,
                 Af[cur ^ 1], Bhs[cur ^ 1], Bls[cur ^ 1]);

    // ---- A fragments: ds_read fp32 (swizzled) -> split to bf16 hi/lo ----
    short8v ah[2], al[2];
#pragma unroll
    for (int mf = 0; mf < 2; ++mf) {
      int row = wave * 32 + mf * 16 + l15;
      int u0 = kb ^ (row & 7);                  // slots j=0..3: k = kb*4+j
      int u1 = (kb + 4) ^ (row & 7);            // slots j=4..7: k = 16+kb*4+j-4
      float4 f0 = *(const float4*)((const char*)Af[cur] + (size_t)row * 128 + u0 * 16);
      float4 f1 = *(const float4*)((const char*)Af[cur] + (size_t)row * 128 + u1 * 16);
      const float e[8] = {f0.x, f0.y, f0.z, f0.w, f1.x, f1.y, f1.z, f1.w};
#pragma unroll
      for (int j = 0; j < 8; ++j) {
        unsigned short h = f2bf(e[j]);
        ah[mf][j] = (short)h;
        al[mf][j] = (short)f2bf(e[j] - bf2f(h));
      }
    }
#pragma unroll
    for (int nf = 0; nf < 8; ++nf) {
      short8v bh = *(const short8v*)((const char*)Bhs[cur] + (size_t)(nf * 16 + l15) * 64 + kb * 16);
      short8v bl = *(const short8v*)((const char*)Bls[cur] + (size_t)(nf * 16 + l15) * 64 + kb * 16);
#pragma unroll
      for (int mf = 0; mf < 2; ++mf) {
        acc[mf][nf] = __builtin_amdgcn_mfma_f32_16x16x32_bf16(ah[mf], bh, acc[mf][nf], 0, 0, 0);
        acc[mf][nf] = __builtin_amdgcn_mfma_f32_16x16x32_bf16(ah[mf], bl, acc[mf][nf], 0, 0, 0);
        acc[mf][nf] = __builtin_amdgcn_mfma_f32_16x16x32_bf16(al[mf], bh, acc[mf][nf], 0, 0, 0);
      }
    }
    __syncthreads();   // drains this iter's DMA (next tile) + all LDS reads
  }

#pragma unroll
  for (int nf = 0; nf < 8; ++nf) {
    float bv = bias[nf * 16 + l15];
#pragma unroll
    for (int mf = 0; mf < 2; ++mf) {
#pragma unroll
      for (int r = 0; r < 4; ++r) {
        int grow = m0 + wave * 32 + mf * 16 + kb * 4 + r;
        if (grow < M) C[(size_t)grow * D_H + nf * 16 + l15] = acc[mf][nf][r] + bv;
      }
    }
  }
}

// ---------------------------------------------------------------------------
// s[n,4] = C[n,128] @ a[4,128]^T  (one wave per row; optional second a)
// ---------------------------------------------------------------------------
__global__ __launch_bounds__(256) void scores_kernel(
    const float* __restrict__ C, int n,
    const float* __restrict__ a0, float* __restrict__ s0,
    const float* __restrict__ a1, float* __restrict__ s1) {
  int wid = (blockIdx.x * blockDim.x + threadIdx.x) >> 6;
  int lane = threadIdx.x & 63;
  if (wid >= n) return;
  float2 v = *(const float2*)&C[(size_t)wid * D_H + lane * 2];
#pragma unroll
  for (int h = 0; h < HEADS; ++h) {
    float p = v.x * a0[h * D_H + lane * 2] + v.y * a0[h * D_H + lane * 2 + 1];
#pragma unroll
    for (int off = 32; off; off >>= 1) p += __shfl_xor(p, off);
    if (lane == 0) s0[wid * HEADS + h] = p;
  }
  if (a1) {
#pragma unroll
    for (int h = 0; h < HEADS; ++h) {
      float p = v.x * a1[h * D_H + lane * 2] + v.y * a1[h * D_H + lane * 2 + 1];
#pragma unroll
      for (int off = 32; off; off >>= 1) p += __shfl_xor(p, off);
      if (lane == 0) s1[wid * HEADS + h] = p;
    }
  }
}

// ---------------------------------------------------------------------------
// Per-edge UNNORMALIZED weights w = exp(leaky_relu(s_src+s_dst)).
// ---------------------------------------------------------------------------
__global__ __launch_bounds__(256) void edge_w_kernel(
    const float* __restrict__ s_src, const float* __restrict__ s_dst,
    const int* __restrict__ src_idx, const int* __restrict__ dst_idx,
    float* __restrict__ wout, int n_edge) {
  int e = blockIdx.x * blockDim.x + threadIdx.x;
  if (e >= n_edge) return;
  int s = src_idx[e], d = dst_idx[e];
  f32x4 a = *(const f32x4*)&s_src[(size_t)s * HEADS];
  f32x4 b = *(const f32x4*)&s_dst[(size_t)d * HEADS];
  f32x4 v = a + b;
  v.x = (v.x >= 0.f) ? v.x : 0.2f * v.x;
  v.y = (v.y >= 0.f) ? v.y : 0.2f * v.y;
  v.z = (v.z >= 0.f) ? v.z : 0.2f * v.z;
  v.w = (v.w >= 0.f) ? v.w : 0.2f * v.w;
  f32x4 w = {__expf(v.x), __expf(v.y), __expf(v.z), __expf(v.w)};
  *(f32x4*)&wout[(size_t)e * HEADS] = w;
}

// ---------------------------------------------------------------------------
// Weighted gather-sum, 2 DST PER WAVE: each 32-lane half owns one dst node
// (lane ll=lane&31 owns dims [ll*4, ll*4+4) -> full 128-dim row per half).
// NO cross-lane merges: den is lane-uniform within a half (every lane adds
// the same w4[e]); acc is fully lane-owned. Epilogue shuffles (r14: 24
// shfl_xor) eliminated; only attend1's fused s_out keeps a 5-step reduce.
// Tail = single edge, no dummy clamped loads.
// ---------------------------------------------------------------------------
__global__ __launch_bounds__(256) void attend_sum_kernel(
    const float* __restrict__ h_src, const float* __restrict__ w4,
    const int* __restrict__ src_idx, const int* __restrict__ rs,
    float* __restrict__ out, int n_dst,
    const float* __restrict__ a_next, float* __restrict__ s_out) {
  int gw = (blockIdx.x * blockDim.x + threadIdx.x) >> 6;   // global wave id
  int lane = threadIdx.x & 63;
  int half = lane >> 5;
  int ll = lane & 31;                // dim group: dims [ll*4, ll*4+4)
  int wid = gw * 2 + half;           // this half's dst node
  if (wid >= n_dst) return;
  int e0 = rs[wid], e1 = rs[wid + 1];

  f32x4 acc0 = {0, 0, 0, 0}, acc1 = acc0, acc2 = acc0, acc3 = acc0;
  f32x4 den = {0, 0, 0, 0};

  int base = e0;
  for (; base + 2 <= e1; base += 2) {          // 2 edges/iter (indep chains)
    int sA = src_idx[base], sB = src_idx[base + 1];
    f32x4 hA = *(const f32x4*)&h_src[(size_t)sA * D_H + ll * 4];
    f32x4 hB = *(const f32x4*)&h_src[(size_t)sB * D_H + ll * 4];
    f32x4 wA = *(const f32x4*)&w4[(size_t)base * HEADS];
    f32x4 wB = *(const f32x4*)&w4[(size_t)(base + 1) * HEADS];
    den += wA; den += wB;
    acc0 = __builtin_elementwise_fma(splat4(wA.x), hA, acc0);
    acc1 = __builtin_elementwise_fma(splat4(wA.y), hA, acc1);
    acc2 = __builtin_elementwise_fma(splat4(wA.z), hA, acc2);
    acc3 = __builtin_elementwise_fma(splat4(wA.w), hA, acc3);
    acc0 = __builtin_elementwise_fma(splat4(wB.x), hB, acc0);
    acc1 = __builtin_elementwise_fma(splat4(wB.y), hB, acc1);
    acc2 = __builtin_elementwise_fma(splat4(wB.z), hB, acc2);
    acc3 = __builtin_elementwise_fma(splat4(wB.w), hB, acc3);
  }
  if (base < e1) {                             // tail: one edge
    int s = src_idx[base];
    f32x4 hv = *(const f32x4*)&h_src[(size_t)s * D_H + ll * 4];
    f32x4 wv = *(const f32x4*)&w4[(size_t)base * HEADS];
    den += wv;
    acc0 = __builtin_elementwise_fma(splat4(wv.x), hv, acc0);
    acc1 = __builtin_elementwise_fma(splat4(wv.y), hv, acc1);
    acc2 = __builtin_elementwise_fma(splat4(wv.z), hv, acc2);
    acc3 = __builtin_elementwise_fma(splat4(wv.w), hv, acc3);
  }

  // den identical across the half's lanes -> no reduction needed
  float rA = den.x > 0.f ? __builtin_amdgcn_rcpf(den.x) : 0.f;
  float rB = den.y > 0.f ? __builtin_amdgcn_rcpf(den.y) : 0.f;
  float rC = den.z > 0.f ? __builtin_amdgcn_rcpf(den.z) : 0.f;
  float rD = den.w > 0.f ? __builtin_amdgcn_rcpf(den.w) : 0.f;
  acc0 *= splat4(rA); acc1 *= splat4(rB); acc2 *= splat4(rC); acc3 *= splat4(rD);
#define ELU4(a) \
  a.x = (a.x > 0.f) ? a.x : (__expf(a.x) - 1.f); \
  a.y = (a.y > 0.f) ? a.y : (__expf(a.y) - 1.f); \
  a.z = (a.z > 0.f) ? a.z : (__expf(a.z) - 1.f); \
  a.w = (a.w > 0.f) ? a.w : (__expf(a.w) - 1.f);
  ELU4(acc0) ELU4(acc1) ELU4(acc2) ELU4(acc3)
#undef ELU4
  f32x4 o = (acc0 + acc1 + acc2 + acc3) * splat4(0.25f);
  *(f32x4*)&out[(size_t)wid * D_H + ll * 4] = o;   // all 32 lanes -> full row

  if (s_out) {  // fused next-layer src scores: reduce within the half
#pragma unroll
    for (int h = 0; h < HEADS; ++h) {
      const float* ah = &a_next[h * D_H + ll * 4];
      float p = o.x * ah[0] + o.y * ah[1] + o.z * ah[2] + o.w * ah[3];
#pragma unroll
      for (int off = 16; off; off >>= 1) p += __shfl_xor(p, off);  // stays in half
      if (ll == 0) s_out[wid * HEADS + h] = p;
    }
  }
}

// ---------------------------------------------------------------------------
extern "C" void kernel_launch(void* const* d_in, const int* in_sizes, int n_in,
                              void* d_out, int out_size, void* d_ws, size_t ws_size,
                              hipStream_t stream) {
  const float* h_user     = (const float*)d_in[0];
  const float* h_item     = (const float*)d_in[1];
  const float* w_user     = (const float*)d_in[2];
  const float* b_user     = (const float*)d_in[3];
  const float* w_item     = (const float*)d_in[4];
  const float* b_item     = (const float*)d_in[5];
  const float* a_user_src = (const float*)d_in[6];
  const float* a_user_dst = (const float*)d_in[7];
  const float* a_item_src = (const float*)d_in[8];
  const float* a_item_dst = (const float*)d_in[9];
  const int* i2u_src = (const int*)d_in[10];
  const int* i2u_dst = (const int*)d_in[11];
  const int* u2i_src = (const int*)d_in[12];
  const int* u2i_dst = (const int*)d_in[13];

  float* out_user = (float*)d_out;                       // hu_new (N_USER,128)
  float* out_item = out_user + (size_t)N_USER * D_H;     // hi_new (N_ITEM,128)

  // workspace layout
  float* hu      = (float*)d_ws;                         // (N_USER,128) 51.2MB
  float* hi      = hu + (size_t)N_USER * D_H;            // (N_ITEM,128)
  float* s_i_src = hi + (size_t)N_ITEM * D_H;            // (N_ITEM,4)
  float* s_i_dst = s_i_src + (size_t)N_ITEM * HEADS;     // (N_ITEM,4)
  float* s_u_dst = s_i_dst + (size_t)N_ITEM * HEADS;     // (N_USER,4)
  float* s_un    = s_u_dst + (size_t)N_USER * HEADS;     // (N_USER,4)
  int* user_rs = (int*)(s_un + (size_t)N_USER * HEADS);  // N_USER+1
  int* item_rs = user_rs + (N_USER + 1);                 // N_ITEM+1
  unsigned short* wtu_hi = (unsigned short*)
      (((uintptr_t)(item_rs + N_ITEM + 1) + 15) & ~(uintptr_t)15);
  unsigned short* wtu_lo = wtu_hi + (size_t)D_IN * D_H;
  unsigned short* wti_hi = wtu_lo + (size_t)D_IN * D_H;
  unsigned short* wti_lo = wti_hi + (size_t)D_IN * D_H;
  // hu is dead after scores_kernel -> alias edge weight buffer into it
  float* wbuf = hu;                                      // (E,4) 12.8MB

  // CSR offsets (edge-parallel run writes)
  hipLaunchKernelGGL(row_offsets_kernel, dim3((N_EDGE + 255) / 256), dim3(256), 0,
                     stream, i2u_dst, N_EDGE, user_rs, N_USER);
  hipLaunchKernelGGL(row_offsets_kernel, dim3((N_EDGE + 255) / 256), dim3(256), 0,
                     stream, u2i_dst, N_EDGE, item_rs, N_ITEM);

  // W prep + FUSED projections (r13-exact GEMM, one dispatch, 1173 blocks)
  hipLaunchKernelGGL(wt_prep_kernel, dim3(D_IN * D_H / 256), dim3(256), 0, stream,
                     w_user, wtu_hi, wtu_lo);
  hipLaunchKernelGGL(wt_prep_kernel, dim3(D_IN * D_H / 256), dim3(256), 0, stream,
                     w_item, wti_hi, wti_lo);
  const int nbu = (N_USER + 127) / 128;                  // 782
  const int nbi = (N_ITEM + 127) / 128;                  // 391
  hipLaunchKernelGGL(gemm_fused_kernel, dim3(nbu + nbi), dim3(256), 0, stream,
                     h_user, h_item, wtu_hi, wtu_lo, wti_hi, wti_lo,
                     b_user, b_item, hu, hi, nbu);

  // per-node attention scores
  hipLaunchKernelGGL(scores_kernel, dim3(N_ITEM / 4), dim3(256), 0, stream,
                     hi, N_ITEM, a_user_src, s_i_src, a_item_dst, s_i_dst);
  hipLaunchKernelGGL(scores_kernel, dim3(N_USER / 4), dim3(256), 0, stream,
                     hu, N_USER, a_user_dst, s_u_dst, (const float*)nullptr, (float*)nullptr);

  // ---- layer 1: items -> users ----  (attend: 8 dst per 256-thr block)
  hipLaunchKernelGGL(edge_w_kernel, dim3((N_EDGE + 255) / 256), dim3(256), 0, stream,
                     s_i_src, s_u_dst, i2u_src, i2u_dst, wbuf, N_EDGE);
  hipLaunchKernelGGL(attend_sum_kernel, dim3((N_USER + 7) / 8), dim3(256), 0, stream,
                     hi, wbuf, i2u_src, user_rs, out_user, N_USER,
                     a_item_src, s_un);

  // ---- layer 2: updated users -> items ----
  hipLaunchKernelGGL(edge_w_kernel, dim3((N_EDGE + 255) / 256), dim3(256), 0, stream,
                     s_un, s_i_dst, u2i_src, u2i_dst, wbuf, N_EDGE);
  hipLaunchKernelGGL(attend_sum_kernel, dim3((N_ITEM + 7) / 8), dim3(256), 0, stream,
                     out_user, wbuf, u2i_src, item_rs, out_item, N_ITEM,
                     (const float*)nullptr, (float*)nullptr);
}

// Round 16
// 284.476 us; speedup vs baseline: 1.1142x; 1.0668x over previous
//
#include <hip/hip_runtime.h>
#include <math.h>

#define N_USER 100000
#define N_ITEM 50000
#define N_EDGE 800000
#define D_IN 256
#define D_H 128
#define HEADS 4

typedef __attribute__((ext_vector_type(8))) short short8v;   // 8 bf16 (4 VGPR)
typedef __attribute__((ext_vector_type(4))) float f32x4;     // 4 fp32

__device__ __forceinline__ unsigned short f2bf(float x) {    // RNE f32->bf16
  unsigned u = __float_as_uint(x);
  return (unsigned short)((u + 0x7FFFu + ((u >> 16) & 1u)) >> 16);
}
__device__ __forceinline__ float bf2f(unsigned short h) {
  return __uint_as_float((unsigned)h << 16);
}
__device__ __forceinline__ f32x4 splat4(float x) { return (f32x4){x, x, x, x}; }

// ---------------------------------------------------------------------------
// CSR row offsets, edge-parallel run writes (each rs[i] written exactly once).
// ---------------------------------------------------------------------------
__global__ void row_offsets_kernel(const int* __restrict__ dst, int n_edge,
                                   int* __restrict__ rs, int n_dst) {
  int e = blockIdx.x * blockDim.x + threadIdx.x;
  if (e >= n_edge) return;
  int d = dst[e];
  int dprev = (e == 0) ? -1 : dst[e - 1];
  for (int i = dprev + 1; i <= d; ++i) rs[i] = e;
  if (e == n_edge - 1)
    for (int i = d + 1; i <= n_dst; ++i) rs[i] = n_edge;
}

// ---------------------------------------------------------------------------
// One-time W prep (RNE split): W[256][128] fp32 -> Wt_hi/Wt_lo[128][256] bf16,
// k permuted to MFMA slot order: pos(k) s.t. slot (kb,j) holds
// k = kb*4 + (j&3) + 16*(j>>2).
// ---------------------------------------------------------------------------
__global__ __launch_bounds__(256) void wt_prep_kernel(
    const float* __restrict__ W, unsigned short* __restrict__ WtHi,
    unsigned short* __restrict__ WtLo) {
  int tid = blockIdx.x * blockDim.x + threadIdx.x;
  if (tid >= D_IN * D_H) return;
  int n = tid & 127, k = tid >> 7;
  float x = W[(size_t)k * D_H + n];
  unsigned short h = f2bf(x);
  unsigned short l = f2bf(x - bf2f(h));
  int kk = k & 31, kbase = k & ~31;
  int pos = (kk < 16) ? ((kk >> 2) * 8 + (kk & 3))
                      : (((kk - 16) >> 2) * 8 + 4 + (kk & 3));
  WtHi[(size_t)n * D_IN + kbase + pos] = h;
  WtLo[(size_t)n * D_IN + kbase + pos] = l;
}

// ---------------------------------------------------------------------------
// Stage one K-step tile (A fp32 128x32 swizzled + B hi/lo 128x32 bf16) into
// LDS entirely via global_load_lds DMA (r13 measured-best structure).
// ---------------------------------------------------------------------------
__device__ __forceinline__ void stage_tile(
    const float* __restrict__ A, const unsigned short* __restrict__ WtHi,
    const unsigned short* __restrict__ WtLo, int m0, int M, int k0,
    int wave, int lane, float* Af, unsigned short* Bh, unsigned short* Bl) {
  // A: wave fills rows wave*32..+31; lane l -> row base+(l>>3), unit l&7.
  // Source pre-swizzled: unit_src = (lane&7) ^ (row&7)  (m104/m173).
#pragma unroll
  for (int i = 0; i < 4; ++i) {
    int rloc = wave * 32 + i * 8 + (lane >> 3);
    int gr = m0 + rloc; if (gr >= M) gr = M - 1;       // clamp; rows never stored
    int u = (lane & 7) ^ (rloc & 7);
    const float* src = A + (size_t)gr * D_IN + k0 + u * 4;
    char* dstb = (char*)Af + (size_t)(wave * 32 + i * 8) * 128;  // wave-uniform
    __builtin_amdgcn_global_load_lds(
        (const __attribute__((address_space(1))) unsigned int*)src,
        (__attribute__((address_space(3))) unsigned int*)dstb, 16, 0, 0);
  }
  // B: row stride 64B; lane l -> row base+(l>>2), 16B unit l&3 (linear).
#pragma unroll
  for (int i = 0; i < 2; ++i) {
    int row = wave * 32 + i * 16 + (lane >> 2);
    int ch = lane & 3;
    const unsigned short* srch = WtHi + (size_t)row * D_IN + k0 + ch * 8;
    char* dsth = (char*)Bh + (size_t)(wave * 32 + i * 16) * 64;
    __builtin_amdgcn_global_load_lds(
        (const __attribute__((address_space(1))) unsigned int*)srch,
        (__attribute__((address_space(3))) unsigned int*)dsth, 16, 0, 0);
    const unsigned short* srcl = WtLo + (size_t)row * D_IN + k0 + ch * 8;
    char* dstl = (char*)Bl + (size_t)(wave * 32 + i * 16) * 64;
    __builtin_amdgcn_global_load_lds(
        (const __attribute__((address_space(1))) unsigned int*)srcl,
        (__attribute__((address_space(3))) unsigned int*)dstl, 16, 0, 0);
  }
}

// ---------------------------------------------------------------------------
// FUSED projections — r13 kernel + bf16 side-copy of the item projection
// (Cbf, consumed by attend1's gather). GEMM core untouched.
// C/D layout (verified m89): col = lane&15, row = (lane>>4)*4 + reg.
// ---------------------------------------------------------------------------
__global__ __launch_bounds__(256) void gemm_fused_kernel(
    const float* __restrict__ Au, const float* __restrict__ Ai,
    const unsigned short* __restrict__ WtUHi, const unsigned short* __restrict__ WtULo,
    const unsigned short* __restrict__ WtIHi, const unsigned short* __restrict__ WtILo,
    const float* __restrict__ bu, const float* __restrict__ bi,
    float* __restrict__ Cu, float* __restrict__ Ci,
    unsigned short* __restrict__ CiBf, int nbu) {
  __shared__ float Af[2][128 * 32];                     // 2 x 16KB
  __shared__ unsigned short Bhs[2][128 * 32];           // 2 x 8KB
  __shared__ unsigned short Bls[2][128 * 32];           // 2 x 8KB  (total 64KB)
  const bool isU = (int)blockIdx.x < nbu;
  const float* A = isU ? Au : Ai;
  const unsigned short* WtHi = isU ? WtUHi : WtIHi;
  const unsigned short* WtLo = isU ? WtULo : WtILo;
  const float* bias = isU ? bu : bi;
  float* C = isU ? Cu : Ci;
  const int M = isU ? N_USER : N_ITEM;
  const int m0 = (isU ? (int)blockIdx.x : (int)blockIdx.x - nbu) * 128;

  const int t = threadIdx.x;
  const int wave = t >> 6, lane = t & 63;
  const int l15 = lane & 15, kb = lane >> 4;

  f32x4 acc[2][8];
#pragma unroll
  for (int mf = 0; mf < 2; ++mf)
#pragma unroll
    for (int nf = 0; nf < 8; ++nf) acc[mf][nf] = (f32x4){0.f, 0.f, 0.f, 0.f};

  stage_tile(A, WtHi, WtLo, m0, M, 0, wave, lane, Af[0], Bhs[0], Bls[0]);
  __syncthreads();                                     // tile 0 ready

#pragma unroll
  for (int ts = 0; ts < 8; ++ts) {
    const int cur = ts & 1;
    if (ts + 1 < 8)                                    // prefetch next tile
      stage_tile(A, WtHi, WtLo, m0, M, (ts + 1) * 32, wave, lane,
                 Af[cur ^ 1], Bhs[cur ^ 1], Bls[cur ^ 1]);

    // ---- A fragments: ds_read fp32 (swizzled) -> split to bf16 hi/lo ----
    short8v ah[2], al[2];
#pragma unroll
    for (int mf = 0; mf < 2; ++mf) {
      int row = wave * 32 + mf * 16 + l15;
      int u0 = kb ^ (row & 7);                  // slots j=0..3: k = kb*4+j
      int u1 = (kb + 4) ^ (row & 7);            // slots j=4..7: k = 16+kb*4+j-4
      float4 f0 = *(const float4*)((const char*)Af[cur] + (size_t)row * 128 + u0 * 16);
      float4 f1 = *(const float4*)((const char*)Af[cur] + (size_t)row * 128 + u1 * 16);
      const float e[8] = {f0.x, f0.y, f0.z, f0.w, f1.x, f1.y, f1.z, f1.w};
#pragma unroll
      for (int j = 0; j < 8; ++j) {
        unsigned short h = f2bf(e[j]);
        ah[mf][j] = (short)h;
        al[mf][j] = (short)f2bf(e[j] - bf2f(h));
      }
    }
#pragma unroll
    for (int nf = 0; nf < 8; ++nf) {
      short8v bh = *(const short8v*)((const char*)Bhs[cur] + (size_t)(nf * 16 + l15) * 64 + kb * 16);
      short8v bl = *(const short8v*)((const char*)Bls[cur] + (size_t)(nf * 16 + l15) * 64 + kb * 16);
#pragma unroll
      for (int mf = 0; mf < 2; ++mf) {
        acc[mf][nf] = __builtin_amdgcn_mfma_f32_16x16x32_bf16(ah[mf], bh, acc[mf][nf], 0, 0, 0);
        acc[mf][nf] = __builtin_amdgcn_mfma_f32_16x16x32_bf16(ah[mf], bl, acc[mf][nf], 0, 0, 0);
        acc[mf][nf] = __builtin_amdgcn_mfma_f32_16x16x32_bf16(al[mf], bh, acc[mf][nf], 0, 0, 0);
      }
    }
    __syncthreads();   // drains this iter's DMA (next tile) + all LDS reads
  }

#pragma unroll
  for (int nf = 0; nf < 8; ++nf) {
    float bv = bias[nf * 16 + l15];
#pragma unroll
    for (int mf = 0; mf < 2; ++mf) {
#pragma unroll
      for (int r = 0; r < 4; ++r) {
        int grow = m0 + wave * 32 + mf * 16 + kb * 4 + r;
        if (grow < M) {
          float v = acc[mf][nf][r] + bv;
          C[(size_t)grow * D_H + nf * 16 + l15] = v;
          if (!isU) CiBf[(size_t)grow * D_H + nf * 16 + l15] = f2bf(v);
        }
      }
    }
  }
}

// ---------------------------------------------------------------------------
// s[n,4] = C[n,128] @ a[4,128]^T  (one wave per row; optional second a)
// ---------------------------------------------------------------------------
__global__ __launch_bounds__(256) void scores_kernel(
    const float* __restrict__ C, int n,
    const float* __restrict__ a0, float* __restrict__ s0,
    const float* __restrict__ a1, float* __restrict__ s1) {
  int wid = (blockIdx.x * blockDim.x + threadIdx.x) >> 6;
  int lane = threadIdx.x & 63;
  if (wid >= n) return;
  float2 v = *(const float2*)&C[(size_t)wid * D_H + lane * 2];
#pragma unroll
  for (int h = 0; h < HEADS; ++h) {
    float p = v.x * a0[h * D_H + lane * 2] + v.y * a0[h * D_H + lane * 2 + 1];
#pragma unroll
    for (int off = 32; off; off >>= 1) p += __shfl_xor(p, off);
    if (lane == 0) s0[wid * HEADS + h] = p;
  }
  if (a1) {
#pragma unroll
    for (int h = 0; h < HEADS; ++h) {
      float p = v.x * a1[h * D_H + lane * 2] + v.y * a1[h * D_H + lane * 2 + 1];
#pragma unroll
      for (int off = 32; off; off >>= 1) p += __shfl_xor(p, off);
      if (lane == 0) s1[wid * HEADS + h] = p;
    }
  }
}

// ---------------------------------------------------------------------------
// Per-edge UNNORMALIZED weights w = exp(leaky_relu(s_src+s_dst)).
// ---------------------------------------------------------------------------
__global__ __launch_bounds__(256) void edge_w_kernel(
    const float* __restrict__ s_src, const float* __restrict__ s_dst,
    const int* __restrict__ src_idx, const int* __restrict__ dst_idx,
    float* __restrict__ wout, int n_edge) {
  int e = blockIdx.x * blockDim.x + threadIdx.x;
  if (e >= n_edge) return;
  int s = src_idx[e], d = dst_idx[e];
  f32x4 a = *(const f32x4*)&s_src[(size_t)s * HEADS];
  f32x4 b = *(const f32x4*)&s_dst[(size_t)d * HEADS];
  f32x4 v = a + b;
  v.x = (v.x >= 0.f) ? v.x : 0.2f * v.x;
  v.y = (v.y >= 0.f) ? v.y : 0.2f * v.y;
  v.z = (v.z >= 0.f) ? v.z : 0.2f * v.z;
  v.w = (v.w >= 0.f) ? v.w : 0.2f * v.w;
  f32x4 w = {__expf(v.x), __expf(v.y), __expf(v.z), __expf(v.w)};
  *(f32x4*)&wout[(size_t)e * HEADS] = w;
}

// ---------------------------------------------------------------------------
// Weighted gather-sum, 2 dst/wave, BF16 GATHER ROWS (halved bytes + cache
// footprint vs r15 fp32). Each 32-lane half owns one dst; lane ll owns dims
// [ll*4, ll*4+4) as ushort4 (8B). den lane-uniform (no reductions).
// Optionally writes a bf16 copy of out (for the next layer's gather) and
// fused next-layer src scores.
// ---------------------------------------------------------------------------
__global__ __launch_bounds__(256) void attend_sum_kernel(
    const unsigned short* __restrict__ h_src, const float* __restrict__ w4,
    const int* __restrict__ src_idx, const int* __restrict__ rs,
    float* __restrict__ out, unsigned short* __restrict__ out_bf, int n_dst,
    const float* __restrict__ a_next, float* __restrict__ s_out) {
  int gw = (blockIdx.x * blockDim.x + threadIdx.x) >> 6;   // global wave id
  int lane = threadIdx.x & 63;
  int half = lane >> 5;
  int ll = lane & 31;                // dim group: dims [ll*4, ll*4+4)
  int wid = gw * 2 + half;           // this half's dst node
  if (wid >= n_dst) return;
  int e0 = rs[wid], e1 = rs[wid + 1];

  f32x4 acc0 = {0, 0, 0, 0}, acc1 = acc0, acc2 = acc0, acc3 = acc0;
  f32x4 den = {0, 0, 0, 0};

  int base = e0;
  for (; base + 2 <= e1; base += 2) {          // 2 edges/iter (indep chains)
    int sA = src_idx[base], sB = src_idx[base + 1];
    ushort4 gA = *(const ushort4*)&h_src[(size_t)sA * D_H + ll * 4];
    ushort4 gB = *(const ushort4*)&h_src[(size_t)sB * D_H + ll * 4];
    f32x4 hA = {bf2f(gA.x), bf2f(gA.y), bf2f(gA.z), bf2f(gA.w)};
    f32x4 hB = {bf2f(gB.x), bf2f(gB.y), bf2f(gB.z), bf2f(gB.w)};
    f32x4 wA = *(const f32x4*)&w4[(size_t)base * HEADS];
    f32x4 wB = *(const f32x4*)&w4[(size_t)(base + 1) * HEADS];
    den += wA; den += wB;
    acc0 = __builtin_elementwise_fma(splat4(wA.x), hA, acc0);
    acc1 = __builtin_elementwise_fma(splat4(wA.y), hA, acc1);
    acc2 = __builtin_elementwise_fma(splat4(wA.z), hA, acc2);
    acc3 = __builtin_elementwise_fma(splat4(wA.w), hA, acc3);
    acc0 = __builtin_elementwise_fma(splat4(wB.x), hB, acc0);
    acc1 = __builtin_elementwise_fma(splat4(wB.y), hB, acc1);
    acc2 = __builtin_elementwise_fma(splat4(wB.z), hB, acc2);
    acc3 = __builtin_elementwise_fma(splat4(wB.w), hB, acc3);
  }
  if (base < e1) {                             // tail: one edge
    int s = src_idx[base];
    ushort4 gv = *(const ushort4*)&h_src[(size_t)s * D_H + ll * 4];
    f32x4 hv = {bf2f(gv.x), bf2f(gv.y), bf2f(gv.z), bf2f(gv.w)};
    f32x4 wv = *(const f32x4*)&w4[(size_t)base * HEADS];
    den += wv;
    acc0 = __builtin_elementwise_fma(splat4(wv.x), hv, acc0);
    acc1 = __builtin_elementwise_fma(splat4(wv.y), hv, acc1);
    acc2 = __builtin_elementwise_fma(splat4(wv.z), hv, acc2);
    acc3 = __builtin_elementwise_fma(splat4(wv.w), hv, acc3);
  }

  // den identical across the half's lanes -> no reduction needed
  float rA = den.x > 0.f ? __builtin_amdgcn_rcpf(den.x) : 0.f;
  float rB = den.y > 0.f ? __builtin_amdgcn_rcpf(den.y) : 0.f;
  float rC = den.z > 0.f ? __builtin_amdgcn_rcpf(den.z) : 0.f;
  float rD = den.w > 0.f ? __builtin_amdgcn_rcpf(den.w) : 0.f;
  acc0 *= splat4(rA); acc1 *= splat4(rB); acc2 *= splat4(rC); acc3 *= splat4(rD);
#define ELU4(a) \
  a.x = (a.x > 0.f) ? a.x : (__expf(a.x) - 1.f); \
  a.y = (a.y > 0.f) ? a.y : (__expf(a.y) - 1.f); \
  a.z = (a.z > 0.f) ? a.z : (__expf(a.z) - 1.f); \
  a.w = (a.w > 0.f) ? a.w : (__expf(a.w) - 1.f);
  ELU4(acc0) ELU4(acc1) ELU4(acc2) ELU4(acc3)
#undef ELU4
  f32x4 o = (acc0 + acc1 + acc2 + acc3) * splat4(0.25f);
  *(f32x4*)&out[(size_t)wid * D_H + ll * 4] = o;   // all 32 lanes -> full row
  if (out_bf) {
    ushort4 ob = {f2bf(o.x), f2bf(o.y), f2bf(o.z), f2bf(o.w)};
    *(ushort4*)&out_bf[(size_t)wid * D_H + ll * 4] = ob;
  }

  if (s_out) {  // fused next-layer src scores: reduce within the half
#pragma unroll
    for (int h = 0; h < HEADS; ++h) {
      const float* ah = &a_next[h * D_H + ll * 4];
      float p = o.x * ah[0] + o.y * ah[1] + o.z * ah[2] + o.w * ah[3];
#pragma unroll
      for (int off = 16; off; off >>= 1) p += __shfl_xor(p, off);  // stays in half
      if (ll == 0) s_out[wid * HEADS + h] = p;
    }
  }
}

// ---------------------------------------------------------------------------
extern "C" void kernel_launch(void* const* d_in, const int* in_sizes, int n_in,
                              void* d_out, int out_size, void* d_ws, size_t ws_size,
                              hipStream_t stream) {
  const float* h_user     = (const float*)d_in[0];
  const float* h_item     = (const float*)d_in[1];
  const float* w_user     = (const float*)d_in[2];
  const float* b_user     = (const float*)d_in[3];
  const float* w_item     = (const float*)d_in[4];
  const float* b_item     = (const float*)d_in[5];
  const float* a_user_src = (const float*)d_in[6];
  const float* a_user_dst = (const float*)d_in[7];
  const float* a_item_src = (const float*)d_in[8];
  const float* a_item_dst = (const float*)d_in[9];
  const int* i2u_src = (const int*)d_in[10];
  const int* i2u_dst = (const int*)d_in[11];
  const int* u2i_src = (const int*)d_in[12];
  const int* u2i_dst = (const int*)d_in[13];

  float* out_user = (float*)d_out;                       // hu_new (N_USER,128)
  float* out_item = out_user + (size_t)N_USER * D_H;     // hi_new (N_ITEM,128)

  // workspace layout (~96MB)
  float* hu      = (float*)d_ws;                         // (N_USER,128) 51.2MB
  float* hi      = hu + (size_t)N_USER * D_H;            // (N_ITEM,128)
  float* s_i_src = hi + (size_t)N_ITEM * D_H;            // (N_ITEM,4)
  float* s_i_dst = s_i_src + (size_t)N_ITEM * HEADS;     // (N_ITEM,4)
  float* s_u_dst = s_i_dst + (size_t)N_ITEM * HEADS;     // (N_USER,4)
  float* s_un    = s_u_dst + (size_t)N_USER * HEADS;     // (N_USER,4)
  int* user_rs = (int*)(s_un + (size_t)N_USER * HEADS);  // N_USER+1
  int* item_rs = user_rs + (N_USER + 1);                 // N_ITEM+1
  unsigned short* wtu_hi = (unsigned short*)
      (((uintptr_t)(item_rs + N_ITEM + 1) + 15) & ~(uintptr_t)15);
  unsigned short* wtu_lo = wtu_hi + (size_t)D_IN * D_H;
  unsigned short* wti_hi = wtu_lo + (size_t)D_IN * D_H;
  unsigned short* wti_lo = wti_hi + (size_t)D_IN * D_H;
  unsigned short* hi_bf  = wti_lo + (size_t)D_IN * D_H;  // (N_ITEM,128) bf16 12.8MB
  // hu is dead after scores_kernel -> alias edge weights + bf16 layer-1 out
  float* wbuf = hu;                                      // (E,4) 12.8MB
  unsigned short* ou_bf = (unsigned short*)(hu + (size_t)N_EDGE * HEADS);  // 25.6MB

  // CSR offsets (edge-parallel run writes)
  hipLaunchKernelGGL(row_offsets_kernel, dim3((N_EDGE + 255) / 256), dim3(256), 0,
                     stream, i2u_dst, N_EDGE, user_rs, N_USER);
  hipLaunchKernelGGL(row_offsets_kernel, dim3((N_EDGE + 255) / 256), dim3(256), 0,
                     stream, u2i_dst, N_EDGE, item_rs, N_ITEM);

  // W prep + FUSED projections (r13-exact GEMM + hi_bf side-copy)
  hipLaunchKernelGGL(wt_prep_kernel, dim3(D_IN * D_H / 256), dim3(256), 0, stream,
                     w_user, wtu_hi, wtu_lo);
  hipLaunchKernelGGL(wt_prep_kernel, dim3(D_IN * D_H / 256), dim3(256), 0, stream,
                     w_item, wti_hi, wti_lo);
  const int nbu = (N_USER + 127) / 128;                  // 782
  const int nbi = (N_ITEM + 127) / 128;                  // 391
  hipLaunchKernelGGL(gemm_fused_kernel, dim3(nbu + nbi), dim3(256), 0, stream,
                     h_user, h_item, wtu_hi, wtu_lo, wti_hi, wti_lo,
                     b_user, b_item, hu, hi, hi_bf, nbu);

  // per-node attention scores
  hipLaunchKernelGGL(scores_kernel, dim3(N_ITEM / 4), dim3(256), 0, stream,
                     hi, N_ITEM, a_user_src, s_i_src, a_item_dst, s_i_dst);
  hipLaunchKernelGGL(scores_kernel, dim3(N_USER / 4), dim3(256), 0, stream,
                     hu, N_USER, a_user_dst, s_u_dst, (const float*)nullptr, (float*)nullptr);

  // ---- layer 1: items -> users ----  (bf16 gather from hi_bf)
  hipLaunchKernelGGL(edge_w_kernel, dim3((N_EDGE + 255) / 256), dim3(256), 0, stream,
                     s_i_src, s_u_dst, i2u_src, i2u_dst, wbuf, N_EDGE);
  hipLaunchKernelGGL(attend_sum_kernel, dim3((N_USER + 7) / 8), dim3(256), 0, stream,
                     hi_bf, wbuf, i2u_src, user_rs, out_user, ou_bf, N_USER,
                     a_item_src, s_un);

  // ---- layer 2: updated users -> items ----  (bf16 gather from ou_bf)
  hipLaunchKernelGGL(edge_w_kernel, dim3((N_EDGE + 255) / 256), dim3(256), 0, stream,
                     s_un, s_i_dst, u2i_src, u2i_dst, wbuf, N_EDGE);
  hipLaunchKernelGGL(attend_sum_kernel, dim3((N_ITEM + 7) / 8), dim3(256), 0, stream,
                     ou_bf, wbuf, u2i_src, item_rs, out_item, (unsigned short*)nullptr,
                     N_ITEM, (const float*)nullptr, (float*)nullptr);
}

// Round 17
// 220.926 us; speedup vs baseline: 1.4347x; 1.2877x over previous
//
#include <hip/hip_runtime.h>
#include <math.h>

#define N_USER 100000
#define N_ITEM 50000
#define N_EDGE 800000
#define D_IN 256
#define D_H 128
#define HEADS 4

typedef __attribute__((ext_vector_type(8))) short short8v;   // 8 bf16 (4 VGPR)
typedef __attribute__((ext_vector_type(4))) float f32x4;     // 4 fp32

__device__ __forceinline__ unsigned short f2bf(float x) {    // RNE f32->bf16
  unsigned u = __float_as_uint(x);
  return (unsigned short)((u + 0x7FFFu + ((u >> 16) & 1u)) >> 16);
}
__device__ __forceinline__ float bf2f(unsigned short h) {
  return __uint_as_float((unsigned)h << 16);
}
__device__ __forceinline__ f32x4 splat4(float x) { return (f32x4){x, x, x, x}; }

// ---------------------------------------------------------------------------
// CSR row offsets, edge-parallel run writes (each rs[i] written exactly once).
// ---------------------------------------------------------------------------
__global__ void row_offsets_kernel(const int* __restrict__ dst, int n_edge,
                                   int* __restrict__ rs, int n_dst) {
  int e = blockIdx.x * blockDim.x + threadIdx.x;
  if (e >= n_edge) return;
  int d = dst[e];
  int dprev = (e == 0) ? -1 : dst[e - 1];
  for (int i = dprev + 1; i <= d; ++i) rs[i] = e;
  if (e == n_edge - 1)
    for (int i = d + 1; i <= n_dst; ++i) rs[i] = n_edge;
}

// ---------------------------------------------------------------------------
// One-time W prep (RNE split): W[256][128] fp32 -> Wt_hi/Wt_lo[128][256] bf16,
// k permuted to MFMA slot order.
// ---------------------------------------------------------------------------
__global__ __launch_bounds__(256) void wt_prep_kernel(
    const float* __restrict__ W, unsigned short* __restrict__ WtHi,
    unsigned short* __restrict__ WtLo) {
  int tid = blockIdx.x * blockDim.x + threadIdx.x;
  if (tid >= D_IN * D_H) return;
  int n = tid & 127, k = tid >> 7;
  float x = W[(size_t)k * D_H + n];
  unsigned short h = f2bf(x);
  unsigned short l = f2bf(x - bf2f(h));
  int kk = k & 31, kbase = k & ~31;
  int pos = (kk < 16) ? ((kk >> 2) * 8 + (kk & 3))
                      : (((kk - 16) >> 2) * 8 + 4 + (kk & 3));
  WtHi[(size_t)n * D_IN + kbase + pos] = h;
  WtLo[(size_t)n * D_IN + kbase + pos] = l;
}

// ---------------------------------------------------------------------------
// Stage one K-step tile (A fp32 128x32 swizzled + B hi/lo 128x32 bf16) into
// LDS entirely via global_load_lds DMA (r13 measured-best structure).
// ---------------------------------------------------------------------------
__device__ __forceinline__ void stage_tile(
    const float* __restrict__ A, const unsigned short* __restrict__ WtHi,
    const unsigned short* __restrict__ WtLo, int m0, int M, int k0,
    int wave, int lane, float* Af, unsigned short* Bh, unsigned short* Bl) {
#pragma unroll
  for (int i = 0; i < 4; ++i) {
    int rloc = wave * 32 + i * 8 + (lane >> 3);
    int gr = m0 + rloc; if (gr >= M) gr = M - 1;       // clamp; rows never stored
    int u = (lane & 7) ^ (rloc & 7);
    const float* src = A + (size_t)gr * D_IN + k0 + u * 4;
    char* dstb = (char*)Af + (size_t)(wave * 32 + i * 8) * 128;  // wave-uniform
    __builtin_amdgcn_global_load_lds(
        (const __attribute__((address_space(1))) unsigned int*)src,
        (__attribute__((address_space(3))) unsigned int*)dstb, 16, 0, 0);
  }
#pragma unroll
  for (int i = 0; i < 2; ++i) {
    int row = wave * 32 + i * 16 + (lane >> 2);
    int ch = lane & 3;
    const unsigned short* srch = WtHi + (size_t)row * D_IN + k0 + ch * 8;
    char* dsth = (char*)Bh + (size_t)(wave * 32 + i * 16) * 64;
    __builtin_amdgcn_global_load_lds(
        (const __attribute__((address_space(1))) unsigned int*)srch,
        (__attribute__((address_space(3))) unsigned int*)dsth, 16, 0, 0);
    const unsigned short* srcl = WtLo + (size_t)row * D_IN + k0 + ch * 8;
    char* dstl = (char*)Bl + (size_t)(wave * 32 + i * 16) * 64;
    __builtin_amdgcn_global_load_lds(
        (const __attribute__((address_space(1))) unsigned int*)srcl,
        (__attribute__((address_space(3))) unsigned int*)dstl, 16, 0, 0);
  }
}

// ---------------------------------------------------------------------------
// FUSED projections + FUSED SCORES (r17): GEMM core = r13-exact. The fp32 C
// is never written; the epilogue computes the per-row attention scores
// directly from registers:
//   user blocks: s_u_dst[row][h] = (row @ a_user_dst[h]) ; nothing else
//   item blocks: hi_bf (bf16) + s_i_src (a_user_src) + s_i_dst (a_item_dst)
// Row layout: row = m0+wave*32+mf*16+kb*4+r held by the 16 lanes sharing kb;
// cols nf*16+l15. shfl_xor offsets 1..8 reduce over l15 (stay in kb group).
// Eliminates both scores_kernel dispatches + 77MB C writes + 77MB re-reads.
// ---------------------------------------------------------------------------
__global__ __launch_bounds__(256) void gemm_fused_kernel(
    const float* __restrict__ Au, const float* __restrict__ Ai,
    const unsigned short* __restrict__ WtUHi, const unsigned short* __restrict__ WtULo,
    const unsigned short* __restrict__ WtIHi, const unsigned short* __restrict__ WtILo,
    const float* __restrict__ bu, const float* __restrict__ bi,
    const float* __restrict__ aUdst, const float* __restrict__ aUsrc,
    const float* __restrict__ aIdst,
    float* __restrict__ sUdst, float* __restrict__ sIsrc,
    float* __restrict__ sIdst,
    unsigned short* __restrict__ CiBf, int nbu) {
  __shared__ float Af[2][128 * 32];                     // 2 x 16KB
  __shared__ unsigned short Bhs[2][128 * 32];           // 2 x 8KB
  __shared__ unsigned short Bls[2][128 * 32];           // 2 x 8KB  (total 64KB)
  const bool isU = (int)blockIdx.x < nbu;
  const float* A = isU ? Au : Ai;
  const unsigned short* WtHi = isU ? WtUHi : WtIHi;
  const unsigned short* WtLo = isU ? WtULo : WtILo;
  const float* bias = isU ? bu : bi;
  const int M = isU ? N_USER : N_ITEM;
  const int m0 = (isU ? (int)blockIdx.x : (int)blockIdx.x - nbu) * 128;

  const int t = threadIdx.x;
  const int wave = t >> 6, lane = t & 63;
  const int l15 = lane & 15, kb = lane >> 4;

  f32x4 acc[2][8];
#pragma unroll
  for (int mf = 0; mf < 2; ++mf)
#pragma unroll
    for (int nf = 0; nf < 8; ++nf) acc[mf][nf] = (f32x4){0.f, 0.f, 0.f, 0.f};

  stage_tile(A, WtHi, WtLo, m0, M, 0, wave, lane, Af[0], Bhs[0], Bls[0]);
  __syncthreads();                                     // tile 0 ready

#pragma unroll
  for (int ts = 0; ts < 8; ++ts) {
    const int cur = ts & 1;
    if (ts + 1 < 8)                                    // prefetch next tile
      stage_tile(A, WtHi, WtLo, m0, M, (ts + 1) * 32, wave, lane,
                 Af[cur ^ 1], Bhs[cur ^ 1], Bls[cur ^ 1]);

    short8v ah[2], al[2];
#pragma unroll
    for (int mf = 0; mf < 2; ++mf) {
      int row = wave * 32 + mf * 16 + l15;
      int u0 = kb ^ (row & 7);
      int u1 = (kb + 4) ^ (row & 7);
      float4 f0 = *(const float4*)((const char*)Af[cur] + (size_t)row * 128 + u0 * 16);
      float4 f1 = *(const float4*)((const char*)Af[cur] + (size_t)row * 128 + u1 * 16);
      const float e[8] = {f0.x, f0.y, f0.z, f0.w, f1.x, f1.y, f1.z, f1.w};
#pragma unroll
      for (int j = 0; j < 8; ++j) {
        unsigned short h = f2bf(e[j]);
        ah[mf][j] = (short)h;
        al[mf][j] = (short)f2bf(e[j] - bf2f(h));
      }
    }
#pragma unroll
    for (int nf = 0; nf < 8; ++nf) {
      short8v bh = *(const short8v*)((const char*)Bhs[cur] + (size_t)(nf * 16 + l15) * 64 + kb * 16);
      short8v bl = *(const short8v*)((const char*)Bls[cur] + (size_t)(nf * 16 + l15) * 64 + kb * 16);
#pragma unroll
      for (int mf = 0; mf < 2; ++mf) {
        acc[mf][nf] = __builtin_amdgcn_mfma_f32_16x16x32_bf16(ah[mf], bh, acc[mf][nf], 0, 0, 0);
        acc[mf][nf] = __builtin_amdgcn_mfma_f32_16x16x32_bf16(ah[mf], bl, acc[mf][nf], 0, 0, 0);
        acc[mf][nf] = __builtin_amdgcn_mfma_f32_16x16x32_bf16(al[mf], bh, acc[mf][nf], 0, 0, 0);
      }
    }
    __syncthreads();   // drains this iter's DMA (next tile) + all LDS reads
  }

  // ---- epilogue: bias fold + fused scores (+ bf16 C for item blocks) ----
  float bv = bias[0];  // placeholder to keep naming simple below
  (void)bv;
  // bf16 C store (item blocks only)
  if (!isU) {
#pragma unroll
    for (int nf = 0; nf < 8; ++nf) {
      float b8 = bias[nf * 16 + l15];
#pragma unroll
      for (int mf = 0; mf < 2; ++mf) {
#pragma unroll
        for (int r = 0; r < 4; ++r) {
          int grow = m0 + wave * 32 + mf * 16 + kb * 4 + r;
          if (grow < M)
            CiBf[(size_t)grow * D_H + nf * 16 + l15] = f2bf(acc[mf][nf][r] + b8);
        }
      }
    }
  }
  // scores: set0 = (user: aUdst -> sUdst) / (item: aUsrc -> sIsrc);
  //         set1 (item only): aIdst -> sIdst
  const float* a0 = isU ? aUdst : aUsrc;
  float* s0 = isU ? sUdst : sIsrc;
#pragma unroll
  for (int h = 0; h < HEADS; ++h) {
    float a0v[8], bd0 = 0.f;
#pragma unroll
    for (int nf = 0; nf < 8; ++nf) {
      a0v[nf] = a0[h * D_H + nf * 16 + l15];
      bd0 = fmaf(bias[nf * 16 + l15], a0v[nf], bd0);
    }
#pragma unroll
    for (int mf = 0; mf < 2; ++mf) {
#pragma unroll
      for (int r = 0; r < 4; ++r) {
        float p = bd0;
#pragma unroll
        for (int nf = 0; nf < 8; ++nf) p = fmaf(acc[mf][nf][r], a0v[nf], p);
        p += __shfl_xor(p, 1); p += __shfl_xor(p, 2);
        p += __shfl_xor(p, 4); p += __shfl_xor(p, 8);
        int grow = m0 + wave * 32 + mf * 16 + kb * 4 + r;
        if (l15 == 0 && grow < M) s0[grow * HEADS + h] = p;
      }
    }
  }
  if (!isU) {
#pragma unroll
    for (int h = 0; h < HEADS; ++h) {
      float a1v[8], bd1 = 0.f;
#pragma unroll
      for (int nf = 0; nf < 8; ++nf) {
        a1v[nf] = aIdst[h * D_H + nf * 16 + l15];
        bd1 = fmaf(bias[nf * 16 + l15], a1v[nf], bd1);
      }
#pragma unroll
      for (int mf = 0; mf < 2; ++mf) {
#pragma unroll
        for (int r = 0; r < 4; ++r) {
          float p = bd1;
#pragma unroll
          for (int nf = 0; nf < 8; ++nf) p = fmaf(acc[mf][nf][r], a1v[nf], p);
          p += __shfl_xor(p, 1); p += __shfl_xor(p, 2);
          p += __shfl_xor(p, 4); p += __shfl_xor(p, 8);
          int grow = m0 + wave * 32 + mf * 16 + kb * 4 + r;
          if (l15 == 0 && grow < M) sIdst[grow * HEADS + h] = p;
        }
      }
    }
  }
}

// ---------------------------------------------------------------------------
// Per-edge UNNORMALIZED weights w = exp(leaky_relu(s_src+s_dst)).
// ---------------------------------------------------------------------------
__global__ __launch_bounds__(256) void edge_w_kernel(
    const float* __restrict__ s_src, const float* __restrict__ s_dst,
    const int* __restrict__ src_idx, const int* __restrict__ dst_idx,
    float* __restrict__ wout, int n_edge) {
  int e = blockIdx.x * blockDim.x + threadIdx.x;
  if (e >= n_edge) return;
  int s = src_idx[e], d = dst_idx[e];
  f32x4 a = *(const f32x4*)&s_src[(size_t)s * HEADS];
  f32x4 b = *(const f32x4*)&s_dst[(size_t)d * HEADS];
  f32x4 v = a + b;
  v.x = (v.x >= 0.f) ? v.x : 0.2f * v.x;
  v.y = (v.y >= 0.f) ? v.y : 0.2f * v.y;
  v.z = (v.z >= 0.f) ? v.z : 0.2f * v.z;
  v.w = (v.w >= 0.f) ? v.w : 0.2f * v.w;
  f32x4 w = {__expf(v.x), __expf(v.y), __expf(v.z), __expf(v.w)};
  *(f32x4*)&wout[(size_t)e * HEADS] = w;
}

// ---------------------------------------------------------------------------
// Weighted gather-sum, 2 dst/wave, bf16 gather rows (r16 measured best).
// ---------------------------------------------------------------------------
__global__ __launch_bounds__(256) void attend_sum_kernel(
    const unsigned short* __restrict__ h_src, const float* __restrict__ w4,
    const int* __restrict__ src_idx, const int* __restrict__ rs,
    float* __restrict__ out, unsigned short* __restrict__ out_bf, int n_dst,
    const float* __restrict__ a_next, float* __restrict__ s_out) {
  int gw = (blockIdx.x * blockDim.x + threadIdx.x) >> 6;   // global wave id
  int lane = threadIdx.x & 63;
  int half = lane >> 5;
  int ll = lane & 31;                // dim group: dims [ll*4, ll*4+4)
  int wid = gw * 2 + half;           // this half's dst node
  if (wid >= n_dst) return;
  int e0 = rs[wid], e1 = rs[wid + 1];

  f32x4 acc0 = {0, 0, 0, 0}, acc1 = acc0, acc2 = acc0, acc3 = acc0;
  f32x4 den = {0, 0, 0, 0};

  int base = e0;
  for (; base + 2 <= e1; base += 2) {
    int sA = src_idx[base], sB = src_idx[base + 1];
    ushort4 gA = *(const ushort4*)&h_src[(size_t)sA * D_H + ll * 4];
    ushort4 gB = *(const ushort4*)&h_src[(size_t)sB * D_H + ll * 4];
    f32x4 hA = {bf2f(gA.x), bf2f(gA.y), bf2f(gA.z), bf2f(gA.w)};
    f32x4 hB = {bf2f(gB.x), bf2f(gB.y), bf2f(gB.z), bf2f(gB.w)};
    f32x4 wA = *(const f32x4*)&w4[(size_t)base * HEADS];
    f32x4 wB = *(const f32x4*)&w4[(size_t)(base + 1) * HEADS];
    den += wA; den += wB;
    acc0 = __builtin_elementwise_fma(splat4(wA.x), hA, acc0);
    acc1 = __builtin_elementwise_fma(splat4(wA.y), hA, acc1);
    acc2 = __builtin_elementwise_fma(splat4(wA.z), hA, acc2);
    acc3 = __builtin_elementwise_fma(splat4(wA.w), hA, acc3);
    acc0 = __builtin_elementwise_fma(splat4(wB.x), hB, acc0);
    acc1 = __builtin_elementwise_fma(splat4(wB.y), hB, acc1);
    acc2 = __builtin_elementwise_fma(splat4(wB.z), hB, acc2);
    acc3 = __builtin_elementwise_fma(splat4(wB.w), hB, acc3);
  }
  if (base < e1) {
    int s = src_idx[base];
    ushort4 gv = *(const ushort4*)&h_src[(size_t)s * D_H + ll * 4];
    f32x4 hv = {bf2f(gv.x), bf2f(gv.y), bf2f(gv.z), bf2f(gv.w)};
    f32x4 wv = *(const f32x4*)&w4[(size_t)base * HEADS];
    den += wv;
    acc0 = __builtin_elementwise_fma(splat4(wv.x), hv, acc0);
    acc1 = __builtin_elementwise_fma(splat4(wv.y), hv, acc1);
    acc2 = __builtin_elementwise_fma(splat4(wv.z), hv, acc2);
    acc3 = __builtin_elementwise_fma(splat4(wv.w), hv, acc3);
  }

  float rA = den.x > 0.f ? __builtin_amdgcn_rcpf(den.x) : 0.f;
  float rB = den.y > 0.f ? __builtin_amdgcn_rcpf(den.y) : 0.f;
  float rC = den.z > 0.f ? __builtin_amdgcn_rcpf(den.z) : 0.f;
  float rD = den.w > 0.f ? __builtin_amdgcn_rcpf(den.w) : 0.f;
  acc0 *= splat4(rA); acc1 *= splat4(rB); acc2 *= splat4(rC); acc3 *= splat4(rD);
#define ELU4(a) \
  a.x = (a.x > 0.f) ? a.x : (__expf(a.x) - 1.f); \
  a.y = (a.y > 0.f) ? a.y : (__expf(a.y) - 1.f); \
  a.z = (a.z > 0.f) ? a.z : (__expf(a.z) - 1.f); \
  a.w = (a.w > 0.f) ? a.w : (__expf(a.w) - 1.f);
  ELU4(acc0) ELU4(acc1) ELU4(acc2) ELU4(acc3)
#undef ELU4
  f32x4 o = (acc0 + acc1 + acc2 + acc3) * splat4(0.25f);
  *(f32x4*)&out[(size_t)wid * D_H + ll * 4] = o;
  if (out_bf) {
    ushort4 ob = {f2bf(o.x), f2bf(o.y), f2bf(o.z), f2bf(o.w)};
    *(ushort4*)&out_bf[(size_t)wid * D_H + ll * 4] = ob;
  }

  if (s_out) {
#pragma unroll
    for (int h = 0; h < HEADS; ++h) {
      const float* ah = &a_next[h * D_H + ll * 4];
      float p = o.x * ah[0] + o.y * ah[1] + o.z * ah[2] + o.w * ah[3];
#pragma unroll
      for (int off = 16; off; off >>= 1) p += __shfl_xor(p, off);
      if (ll == 0) s_out[wid * HEADS + h] = p;
    }
  }
}

// ---------------------------------------------------------------------------
extern "C" void kernel_launch(void* const* d_in, const int* in_sizes, int n_in,
                              void* d_out, int out_size, void* d_ws, size_t ws_size,
                              hipStream_t stream) {
  const float* h_user     = (const float*)d_in[0];
  const float* h_item     = (const float*)d_in[1];
  const float* w_user     = (const float*)d_in[2];
  const float* b_user     = (const float*)d_in[3];
  const float* w_item     = (const float*)d_in[4];
  const float* b_item     = (const float*)d_in[5];
  const float* a_user_src = (const float*)d_in[6];
  const float* a_user_dst = (const float*)d_in[7];
  const float* a_item_src = (const float*)d_in[8];
  const float* a_item_dst = (const float*)d_in[9];
  const int* i2u_src = (const int*)d_in[10];
  const int* i2u_dst = (const int*)d_in[11];
  const int* u2i_src = (const int*)d_in[12];
  const int* u2i_dst = (const int*)d_in[13];

  float* out_user = (float*)d_out;                       // hu_new (N_USER,128)
  float* out_item = out_user + (size_t)N_USER * D_H;     // hi_new (N_ITEM,128)

  // workspace layout (fp32 hu/hi regions now dead; reused for wbuf/ou_bf)
  float* hu      = (float*)d_ws;                         // (reused region)
  float* hi      = hu + (size_t)N_USER * D_H;
  float* s_i_src = hi + (size_t)N_ITEM * D_H;            // (N_ITEM,4)
  float* s_i_dst = s_i_src + (size_t)N_ITEM * HEADS;     // (N_ITEM,4)
  float* s_u_dst = s_i_dst + (size_t)N_ITEM * HEADS;     // (N_USER,4)
  float* s_un    = s_u_dst + (size_t)N_USER * HEADS;     // (N_USER,4)
  int* user_rs = (int*)(s_un + (size_t)N_USER * HEADS);  // N_USER+1
  int* item_rs = user_rs + (N_USER + 1);                 // N_ITEM+1
  unsigned short* wtu_hi = (unsigned short*)
      (((uintptr_t)(item_rs + N_ITEM + 1) + 15) & ~(uintptr_t)15);
  unsigned short* wtu_lo = wtu_hi + (size_t)D_IN * D_H;
  unsigned short* wti_hi = wtu_lo + (size_t)D_IN * D_H;
  unsigned short* wti_lo = wti_hi + (size_t)D_IN * D_H;
  unsigned short* hi_bf  = wti_lo + (size_t)D_IN * D_H;  // (N_ITEM,128) bf16 12.8MB
  float* wbuf = hu;                                      // (E,4) 12.8MB
  unsigned short* ou_bf = (unsigned short*)(hu + (size_t)N_EDGE * HEADS);  // 25.6MB

  // CSR offsets (edge-parallel run writes)
  hipLaunchKernelGGL(row_offsets_kernel, dim3((N_EDGE + 255) / 256), dim3(256), 0,
                     stream, i2u_dst, N_EDGE, user_rs, N_USER);
  hipLaunchKernelGGL(row_offsets_kernel, dim3((N_EDGE + 255) / 256), dim3(256), 0,
                     stream, u2i_dst, N_EDGE, item_rs, N_ITEM);

  // W prep + FUSED projections+scores (one dispatch, 1173 blocks)
  hipLaunchKernelGGL(wt_prep_kernel, dim3(D_IN * D_H / 256), dim3(256), 0, stream,
                     w_user, wtu_hi, wtu_lo);
  hipLaunchKernelGGL(wt_prep_kernel, dim3(D_IN * D_H / 256), dim3(256), 0, stream,
                     w_item, wti_hi, wti_lo);
  const int nbu = (N_USER + 127) / 128;                  // 782
  const int nbi = (N_ITEM + 127) / 128;                  // 391
  hipLaunchKernelGGL(gemm_fused_kernel, dim3(nbu + nbi), dim3(256), 0, stream,
                     h_user, h_item, wtu_hi, wtu_lo, wti_hi, wti_lo,
                     b_user, b_item,
                     a_user_dst, a_user_src, a_item_dst,
                     s_u_dst, s_i_src, s_i_dst, hi_bf, nbu);

  // ---- layer 1: items -> users ----  (bf16 gather from hi_bf)
  hipLaunchKernelGGL(edge_w_kernel, dim3((N_EDGE + 255) / 256), dim3(256), 0, stream,
                     s_i_src, s_u_dst, i2u_src, i2u_dst, wbuf, N_EDGE);
  hipLaunchKernelGGL(attend_sum_kernel, dim3((N_USER + 7) / 8), dim3(256), 0, stream,
                     hi_bf, wbuf, i2u_src, user_rs, out_user, ou_bf, N_USER,
                     a_item_src, s_un);

  // ---- layer 2: updated users -> items ----  (bf16 gather from ou_bf)
  hipLaunchKernelGGL(edge_w_kernel, dim3((N_EDGE + 255) / 256), dim3(256), 0, stream,
                     s_un, s_i_dst, u2i_src, u2i_dst, wbuf, N_EDGE);
  hipLaunchKernelGGL(attend_sum_kernel, dim3((N_ITEM + 7) / 8), dim3(256), 0, stream,
                     ou_bf, wbuf, u2i_src, item_rs, out_item, (unsigned short*)nullptr,
                     N_ITEM, (const float*)nullptr, (float*)nullptr);
}

// Round 18
// 220.777 us; speedup vs baseline: 1.4357x; 1.0007x over previous
//
#include <hip/hip_runtime.h>
#include <math.h>

#define N_USER 100000
#define N_ITEM 50000
#define N_EDGE 800000
#define D_IN 256
#define D_H 128
#define HEADS 4

typedef __attribute__((ext_vector_type(8))) short short8v;   // 8 bf16 (4 VGPR)
typedef __attribute__((ext_vector_type(4))) float f32x4;     // 4 fp32

__device__ __forceinline__ unsigned short f2bf(float x) {    // RNE f32->bf16
  unsigned u = __float_as_uint(x);
  return (unsigned short)((u + 0x7FFFu + ((u >> 16) & 1u)) >> 16);
}
__device__ __forceinline__ float bf2f(unsigned short h) {
  return __uint_as_float((unsigned)h << 16);
}
__device__ __forceinline__ f32x4 splat4(float x) { return (f32x4){x, x, x, x}; }

// ---------------------------------------------------------------------------
// CSR row offsets, edge-parallel run writes (each rs[i] written exactly once).
// ---------------------------------------------------------------------------
__global__ void row_offsets_kernel(const int* __restrict__ dst, int n_edge,
                                   int* __restrict__ rs, int n_dst) {
  int e = blockIdx.x * blockDim.x + threadIdx.x;
  if (e >= n_edge) return;
  int d = dst[e];
  int dprev = (e == 0) ? -1 : dst[e - 1];
  for (int i = dprev + 1; i <= d; ++i) rs[i] = e;
  if (e == n_edge - 1)
    for (int i = d + 1; i <= n_dst; ++i) rs[i] = n_edge;
}

// ---------------------------------------------------------------------------
// One-time W prep (RNE split): W[256][128] fp32 -> Wt_hi/Wt_lo[128][256] bf16,
// k permuted to MFMA slot order.
// ---------------------------------------------------------------------------
__global__ __launch_bounds__(256) void wt_prep_kernel(
    const float* __restrict__ W, unsigned short* __restrict__ WtHi,
    unsigned short* __restrict__ WtLo) {
  int tid = blockIdx.x * blockDim.x + threadIdx.x;
  if (tid >= D_IN * D_H) return;
  int n = tid & 127, k = tid >> 7;
  float x = W[(size_t)k * D_H + n];
  unsigned short h = f2bf(x);
  unsigned short l = f2bf(x - bf2f(h));
  int kk = k & 31, kbase = k & ~31;
  int pos = (kk < 16) ? ((kk >> 2) * 8 + (kk & 3))
                      : (((kk - 16) >> 2) * 8 + 4 + (kk & 3));
  WtHi[(size_t)n * D_IN + kbase + pos] = h;
  WtLo[(size_t)n * D_IN + kbase + pos] = l;
}

// ---------------------------------------------------------------------------
// Stage one K-step tile (A fp32 128x32 swizzled + B hi/lo 128x32 bf16) into
// LDS entirely via global_load_lds DMA (r13 measured-best structure).
// ---------------------------------------------------------------------------
__device__ __forceinline__ void stage_tile(
    const float* __restrict__ A, const unsigned short* __restrict__ WtHi,
    const unsigned short* __restrict__ WtLo, int m0, int M, int k0,
    int wave, int lane, float* Af, unsigned short* Bh, unsigned short* Bl) {
#pragma unroll
  for (int i = 0; i < 4; ++i) {
    int rloc = wave * 32 + i * 8 + (lane >> 3);
    int gr = m0 + rloc; if (gr >= M) gr = M - 1;       // clamp; rows never stored
    int u = (lane & 7) ^ (rloc & 7);
    const float* src = A + (size_t)gr * D_IN + k0 + u * 4;
    char* dstb = (char*)Af + (size_t)(wave * 32 + i * 8) * 128;  // wave-uniform
    __builtin_amdgcn_global_load_lds(
        (const __attribute__((address_space(1))) unsigned int*)src,
        (__attribute__((address_space(3))) unsigned int*)dstb, 16, 0, 0);
  }
#pragma unroll
  for (int i = 0; i < 2; ++i) {
    int row = wave * 32 + i * 16 + (lane >> 2);
    int ch = lane & 3;
    const unsigned short* srch = WtHi + (size_t)row * D_IN + k0 + ch * 8;
    char* dsth = (char*)Bh + (size_t)(wave * 32 + i * 16) * 64;
    __builtin_amdgcn_global_load_lds(
        (const __attribute__((address_space(1))) unsigned int*)srch,
        (__attribute__((address_space(3))) unsigned int*)dsth, 16, 0, 0);
    const unsigned short* srcl = WtLo + (size_t)row * D_IN + k0 + ch * 8;
    char* dstl = (char*)Bl + (size_t)(wave * 32 + i * 16) * 64;
    __builtin_amdgcn_global_load_lds(
        (const __attribute__((address_space(1))) unsigned int*)srcl,
        (__attribute__((address_space(3))) unsigned int*)dstl, 16, 0, 0);
  }
}

// ---------------------------------------------------------------------------
// FUSED projections + FUSED SCORES (r17-exact, measured 220.9 total):
// fp32 C never written; epilogue emits per-row scores from registers and
// the bf16 item projection (hi_bf).
// C/D layout (verified m89): col = lane&15, row = (lane>>4)*4 + reg.
// ---------------------------------------------------------------------------
__global__ __launch_bounds__(256) void gemm_fused_kernel(
    const float* __restrict__ Au, const float* __restrict__ Ai,
    const unsigned short* __restrict__ WtUHi, const unsigned short* __restrict__ WtULo,
    const unsigned short* __restrict__ WtIHi, const unsigned short* __restrict__ WtILo,
    const float* __restrict__ bu, const float* __restrict__ bi,
    const float* __restrict__ aUdst, const float* __restrict__ aUsrc,
    const float* __restrict__ aIdst,
    float* __restrict__ sUdst, float* __restrict__ sIsrc,
    float* __restrict__ sIdst,
    unsigned short* __restrict__ CiBf, int nbu) {
  __shared__ float Af[2][128 * 32];                     // 2 x 16KB
  __shared__ unsigned short Bhs[2][128 * 32];           // 2 x 8KB
  __shared__ unsigned short Bls[2][128 * 32];           // 2 x 8KB  (total 64KB)
  const bool isU = (int)blockIdx.x < nbu;
  const float* A = isU ? Au : Ai;
  const unsigned short* WtHi = isU ? WtUHi : WtIHi;
  const unsigned short* WtLo = isU ? WtULo : WtILo;
  const float* bias = isU ? bu : bi;
  const int M = isU ? N_USER : N_ITEM;
  const int m0 = (isU ? (int)blockIdx.x : (int)blockIdx.x - nbu) * 128;

  const int t = threadIdx.x;
  const int wave = t >> 6, lane = t & 63;
  const int l15 = lane & 15, kb = lane >> 4;

  f32x4 acc[2][8];
#pragma unroll
  for (int mf = 0; mf < 2; ++mf)
#pragma unroll
    for (int nf = 0; nf < 8; ++nf) acc[mf][nf] = (f32x4){0.f, 0.f, 0.f, 0.f};

  stage_tile(A, WtHi, WtLo, m0, M, 0, wave, lane, Af[0], Bhs[0], Bls[0]);
  __syncthreads();                                     // tile 0 ready

#pragma unroll
  for (int ts = 0; ts < 8; ++ts) {
    const int cur = ts & 1;
    if (ts + 1 < 8)                                    // prefetch next tile
      stage_tile(A, WtHi, WtLo, m0, M, (ts + 1) * 32, wave, lane,
                 Af[cur ^ 1], Bhs[cur ^ 1], Bls[cur ^ 1]);

    short8v ah[2], al[2];
#pragma unroll
    for (int mf = 0; mf < 2; ++mf) {
      int row = wave * 32 + mf * 16 + l15;
      int u0 = kb ^ (row & 7);
      int u1 = (kb + 4) ^ (row & 7);
      float4 f0 = *(const float4*)((const char*)Af[cur] + (size_t)row * 128 + u0 * 16);
      float4 f1 = *(const float4*)((const char*)Af[cur] + (size_t)row * 128 + u1 * 16);
      const float e[8] = {f0.x, f0.y, f0.z, f0.w, f1.x, f1.y, f1.z, f1.w};
#pragma unroll
      for (int j = 0; j < 8; ++j) {
        unsigned short h = f2bf(e[j]);
        ah[mf][j] = (short)h;
        al[mf][j] = (short)f2bf(e[j] - bf2f(h));
      }
    }
#pragma unroll
    for (int nf = 0; nf < 8; ++nf) {
      short8v bh = *(const short8v*)((const char*)Bhs[cur] + (size_t)(nf * 16 + l15) * 64 + kb * 16);
      short8v bl = *(const short8v*)((const char*)Bls[cur] + (size_t)(nf * 16 + l15) * 64 + kb * 16);
#pragma unroll
      for (int mf = 0; mf < 2; ++mf) {
        acc[mf][nf] = __builtin_amdgcn_mfma_f32_16x16x32_bf16(ah[mf], bh, acc[mf][nf], 0, 0, 0);
        acc[mf][nf] = __builtin_amdgcn_mfma_f32_16x16x32_bf16(ah[mf], bl, acc[mf][nf], 0, 0, 0);
        acc[mf][nf] = __builtin_amdgcn_mfma_f32_16x16x32_bf16(al[mf], bh, acc[mf][nf], 0, 0, 0);
      }
    }
    __syncthreads();   // drains this iter's DMA (next tile) + all LDS reads
  }

  // ---- epilogue: bf16 C (item) + fused scores ----
  if (!isU) {
#pragma unroll
    for (int nf = 0; nf < 8; ++nf) {
      float b8 = bias[nf * 16 + l15];
#pragma unroll
      for (int mf = 0; mf < 2; ++mf) {
#pragma unroll
        for (int r = 0; r < 4; ++r) {
          int grow = m0 + wave * 32 + mf * 16 + kb * 4 + r;
          if (grow < M)
            CiBf[(size_t)grow * D_H + nf * 16 + l15] = f2bf(acc[mf][nf][r] + b8);
        }
      }
    }
  }
  const float* a0 = isU ? aUdst : aUsrc;
  float* s0 = isU ? sUdst : sIsrc;
#pragma unroll
  for (int h = 0; h < HEADS; ++h) {
    float a0v[8], bd0 = 0.f;
#pragma unroll
    for (int nf = 0; nf < 8; ++nf) {
      a0v[nf] = a0[h * D_H + nf * 16 + l15];
      bd0 = fmaf(bias[nf * 16 + l15], a0v[nf], bd0);
    }
#pragma unroll
    for (int mf = 0; mf < 2; ++mf) {
#pragma unroll
      for (int r = 0; r < 4; ++r) {
        float p = bd0;
#pragma unroll
        for (int nf = 0; nf < 8; ++nf) p = fmaf(acc[mf][nf][r], a0v[nf], p);
        p += __shfl_xor(p, 1); p += __shfl_xor(p, 2);
        p += __shfl_xor(p, 4); p += __shfl_xor(p, 8);
        int grow = m0 + wave * 32 + mf * 16 + kb * 4 + r;
        if (l15 == 0 && grow < M) s0[grow * HEADS + h] = p;
      }
    }
  }
  if (!isU) {
#pragma unroll
    for (int h = 0; h < HEADS; ++h) {
      float a1v[8], bd1 = 0.f;
#pragma unroll
      for (int nf = 0; nf < 8; ++nf) {
        a1v[nf] = aIdst[h * D_H + nf * 16 + l15];
        bd1 = fmaf(bias[nf * 16 + l15], a1v[nf], bd1);
      }
#pragma unroll
      for (int mf = 0; mf < 2; ++mf) {
#pragma unroll
        for (int r = 0; r < 4; ++r) {
          float p = bd1;
#pragma unroll
          for (int nf = 0; nf < 8; ++nf) p = fmaf(acc[mf][nf][r], a1v[nf], p);
          p += __shfl_xor(p, 1); p += __shfl_xor(p, 2);
          p += __shfl_xor(p, 4); p += __shfl_xor(p, 8);
          int grow = m0 + wave * 32 + mf * 16 + kb * 4 + r;
          if (l15 == 0 && grow < M) sIdst[grow * HEADS + h] = p;
        }
      }
    }
  }
}

// ---------------------------------------------------------------------------
// Weighted gather-sum with INLINE EDGE WEIGHTS (r18): w = exp(leaky_relu(
// s_src[s] + s_dst[wid])) computed in the gather loop (s_dst loaded once per
// dst; s_src[s] is a 16B L2-resident gather replacing the former w4[e] load).
// Eliminates the edge_w pass (2 dispatches + 51MB wbuf traffic).
// 2 dst/wave, bf16 gather rows; den lane-uniform (no reductions).
// ---------------------------------------------------------------------------
__global__ __launch_bounds__(256) void attend_sum_kernel(
    const unsigned short* __restrict__ h_src, const float* __restrict__ s_src,
    const float* __restrict__ s_dst, const int* __restrict__ src_idx,
    const int* __restrict__ rs, float* __restrict__ out,
    unsigned short* __restrict__ out_bf, int n_dst,
    const float* __restrict__ a_next, float* __restrict__ s_out) {
  int gw = (blockIdx.x * blockDim.x + threadIdx.x) >> 6;   // global wave id
  int lane = threadIdx.x & 63;
  int half = lane >> 5;
  int ll = lane & 31;                // dim group: dims [ll*4, ll*4+4)
  int wid = gw * 2 + half;           // this half's dst node
  if (wid >= n_dst) return;
  int e0 = rs[wid], e1 = rs[wid + 1];
  f32x4 sd = *(const f32x4*)&s_dst[(size_t)wid * HEADS];

#define EDGE_W(sv, wv) {                                                    \
    f32x4 v_ = sv + sd;                                                     \
    v_.x = (v_.x >= 0.f) ? v_.x : 0.2f * v_.x;                              \
    v_.y = (v_.y >= 0.f) ? v_.y : 0.2f * v_.y;                              \
    v_.z = (v_.z >= 0.f) ? v_.z : 0.2f * v_.z;                              \
    v_.w = (v_.w >= 0.f) ? v_.w : 0.2f * v_.w;                              \
    wv = (f32x4){__expf(v_.x), __expf(v_.y), __expf(v_.z), __expf(v_.w)};   \
  }

  f32x4 acc0 = {0, 0, 0, 0}, acc1 = acc0, acc2 = acc0, acc3 = acc0;
  f32x4 den = {0, 0, 0, 0};

  int base = e0;
  for (; base + 2 <= e1; base += 2) {
    int sA = src_idx[base], sB = src_idx[base + 1];
    ushort4 gA = *(const ushort4*)&h_src[(size_t)sA * D_H + ll * 4];
    ushort4 gB = *(const ushort4*)&h_src[(size_t)sB * D_H + ll * 4];
    f32x4 svA = *(const f32x4*)&s_src[(size_t)sA * HEADS];
    f32x4 svB = *(const f32x4*)&s_src[(size_t)sB * HEADS];
    f32x4 hA = {bf2f(gA.x), bf2f(gA.y), bf2f(gA.z), bf2f(gA.w)};
    f32x4 hB = {bf2f(gB.x), bf2f(gB.y), bf2f(gB.z), bf2f(gB.w)};
    f32x4 wA, wB;
    EDGE_W(svA, wA); EDGE_W(svB, wB);
    den += wA; den += wB;
    acc0 = __builtin_elementwise_fma(splat4(wA.x), hA, acc0);
    acc1 = __builtin_elementwise_fma(splat4(wA.y), hA, acc1);
    acc2 = __builtin_elementwise_fma(splat4(wA.z), hA, acc2);
    acc3 = __builtin_elementwise_fma(splat4(wA.w), hA, acc3);
    acc0 = __builtin_elementwise_fma(splat4(wB.x), hB, acc0);
    acc1 = __builtin_elementwise_fma(splat4(wB.y), hB, acc1);
    acc2 = __builtin_elementwise_fma(splat4(wB.z), hB, acc2);
    acc3 = __builtin_elementwise_fma(splat4(wB.w), hB, acc3);
  }
  if (base < e1) {
    int s = src_idx[base];
    ushort4 gv = *(const ushort4*)&h_src[(size_t)s * D_H + ll * 4];
    f32x4 sv = *(const f32x4*)&s_src[(size_t)s * HEADS];
    f32x4 hv = {bf2f(gv.x), bf2f(gv.y), bf2f(gv.z), bf2f(gv.w)};
    f32x4 wv;
    EDGE_W(sv, wv);
    den += wv;
    acc0 = __builtin_elementwise_fma(splat4(wv.x), hv, acc0);
    acc1 = __builtin_elementwise_fma(splat4(wv.y), hv, acc1);
    acc2 = __builtin_elementwise_fma(splat4(wv.z), hv, acc2);
    acc3 = __builtin_elementwise_fma(splat4(wv.w), hv, acc3);
  }
#undef EDGE_W

  float rA = den.x > 0.f ? __builtin_amdgcn_rcpf(den.x) : 0.f;
  float rB = den.y > 0.f ? __builtin_amdgcn_rcpf(den.y) : 0.f;
  float rC = den.z > 0.f ? __builtin_amdgcn_rcpf(den.z) : 0.f;
  float rD = den.w > 0.f ? __builtin_amdgcn_rcpf(den.w) : 0.f;
  acc0 *= splat4(rA); acc1 *= splat4(rB); acc2 *= splat4(rC); acc3 *= splat4(rD);
#define ELU4(a) \
  a.x = (a.x > 0.f) ? a.x : (__expf(a.x) - 1.f); \
  a.y = (a.y > 0.f) ? a.y : (__expf(a.y) - 1.f); \
  a.z = (a.z > 0.f) ? a.z : (__expf(a.z) - 1.f); \
  a.w = (a.w > 0.f) ? a.w : (__expf(a.w) - 1.f);
  ELU4(acc0) ELU4(acc1) ELU4(acc2) ELU4(acc3)
#undef ELU4
  f32x4 o = (acc0 + acc1 + acc2 + acc3) * splat4(0.25f);
  *(f32x4*)&out[(size_t)wid * D_H + ll * 4] = o;
  if (out_bf) {
    ushort4 ob = {f2bf(o.x), f2bf(o.y), f2bf(o.z), f2bf(o.w)};
    *(ushort4*)&out_bf[(size_t)wid * D_H + ll * 4] = ob;
  }

  if (s_out) {  // fused next-layer src scores: reduce within the half
#pragma unroll
    for (int h = 0; h < HEADS; ++h) {
      const float* ah = &a_next[h * D_H + ll * 4];
      float p = o.x * ah[0] + o.y * ah[1] + o.z * ah[2] + o.w * ah[3];
#pragma unroll
      for (int off = 16; off; off >>= 1) p += __shfl_xor(p, off);
      if (ll == 0) s_out[wid * HEADS + h] = p;
    }
  }
}

// ---------------------------------------------------------------------------
extern "C" void kernel_launch(void* const* d_in, const int* in_sizes, int n_in,
                              void* d_out, int out_size, void* d_ws, size_t ws_size,
                              hipStream_t stream) {
  const float* h_user     = (const float*)d_in[0];
  const float* h_item     = (const float*)d_in[1];
  const float* w_user     = (const float*)d_in[2];
  const float* b_user     = (const float*)d_in[3];
  const float* w_item     = (const float*)d_in[4];
  const float* b_item     = (const float*)d_in[5];
  const float* a_user_src = (const float*)d_in[6];
  const float* a_user_dst = (const float*)d_in[7];
  const float* a_item_src = (const float*)d_in[8];
  const float* a_item_dst = (const float*)d_in[9];
  const int* i2u_src = (const int*)d_in[10];
  const int* i2u_dst = (const int*)d_in[11];
  const int* u2i_src = (const int*)d_in[12];
  const int* u2i_dst = (const int*)d_in[13];

  float* out_user = (float*)d_out;                       // hu_new (N_USER,128)
  float* out_item = out_user + (size_t)N_USER * D_H;     // hi_new (N_ITEM,128)

  // workspace layout
  float* base_f  = (float*)d_ws;
  unsigned short* ou_bf = (unsigned short*)base_f;       // (N_USER,128) bf16 25.6MB
  float* s_i_src = (float*)(ou_bf + (size_t)N_USER * D_H);  // (N_ITEM,4)
  float* s_i_dst = s_i_src + (size_t)N_ITEM * HEADS;     // (N_ITEM,4)
  float* s_u_dst = s_i_dst + (size_t)N_ITEM * HEADS;     // (N_USER,4)
  float* s_un    = s_u_dst + (size_t)N_USER * HEADS;     // (N_USER,4)
  int* user_rs = (int*)(s_un + (size_t)N_USER * HEADS);  // N_USER+1
  int* item_rs = user_rs + (N_USER + 1);                 // N_ITEM+1
  unsigned short* wtu_hi = (unsigned short*)
      (((uintptr_t)(item_rs + N_ITEM + 1) + 15) & ~(uintptr_t)15);
  unsigned short* wtu_lo = wtu_hi + (size_t)D_IN * D_H;
  unsigned short* wti_hi = wtu_lo + (size_t)D_IN * D_H;
  unsigned short* wti_lo = wti_hi + (size_t)D_IN * D_H;
  unsigned short* hi_bf  = wti_lo + (size_t)D_IN * D_H;  // (N_ITEM,128) bf16 12.8MB

  // CSR offsets (edge-parallel run writes)
  hipLaunchKernelGGL(row_offsets_kernel, dim3((N_EDGE + 255) / 256), dim3(256), 0,
                     stream, i2u_dst, N_EDGE, user_rs, N_USER);
  hipLaunchKernelGGL(row_offsets_kernel, dim3((N_EDGE + 255) / 256), dim3(256), 0,
                     stream, u2i_dst, N_EDGE, item_rs, N_ITEM);

  // W prep + FUSED projections+scores (one dispatch, 1173 blocks)
  hipLaunchKernelGGL(wt_prep_kernel, dim3(D_IN * D_H / 256), dim3(256), 0, stream,
                     w_user, wtu_hi, wtu_lo);
  hipLaunchKernelGGL(wt_prep_kernel, dim3(D_IN * D_H / 256), dim3(256), 0, stream,
                     w_item, wti_hi, wti_lo);
  const int nbu = (N_USER + 127) / 128;                  // 782
  const int nbi = (N_ITEM + 127) / 128;                  // 391
  hipLaunchKernelGGL(gemm_fused_kernel, dim3(nbu + nbi), dim3(256), 0, stream,
                     h_user, h_item, wtu_hi, wtu_lo, wti_hi, wti_lo,
                     b_user, b_item,
                     a_user_dst, a_user_src, a_item_dst,
                     s_u_dst, s_i_src, s_i_dst, hi_bf, nbu);

  // ---- layer 1: items -> users ----  (bf16 gather; inline edge weights)
  hipLaunchKernelGGL(attend_sum_kernel, dim3((N_USER + 7) / 8), dim3(256), 0, stream,
                     hi_bf, s_i_src, s_u_dst, i2u_src, user_rs,
                     out_user, ou_bf, N_USER, a_item_src, s_un);

  // ---- layer 2: updated users -> items ----
  hipLaunchKernelGGL(attend_sum_kernel, dim3((N_ITEM + 7) / 8), dim3(256), 0, stream,
                     ou_bf, s_un, s_i_dst, u2i_src, item_rs,
                     out_item, (unsigned short*)nullptr, N_ITEM,
                     (const float*)nullptr, (float*)nullptr);
}

// Round 19
// 216.816 us; speedup vs baseline: 1.4619x; 1.0183x over previous
//
#include <hip/hip_runtime.h>
#include <math.h>

#define N_USER 100000
#define N_ITEM 50000
#define N_EDGE 800000
#define D_IN 256
#define D_H 128
#define HEADS 4

typedef __attribute__((ext_vector_type(8))) short short8v;   // 8 bf16 (4 VGPR)
typedef __attribute__((ext_vector_type(4))) float f32x4;     // 4 fp32

__device__ __forceinline__ unsigned short f2bf(float x) {    // RNE f32->bf16
  unsigned u = __float_as_uint(x);
  return (unsigned short)((u + 0x7FFFu + ((u >> 16) & 1u)) >> 16);
}
__device__ __forceinline__ float bf2f(unsigned short h) {
  return __uint_as_float((unsigned)h << 16);
}
__device__ __forceinline__ f32x4 splat4(float x) { return (f32x4){x, x, x, x}; }

// ---------------------------------------------------------------------------
// CSR row offsets, edge-parallel run writes (each rs[i] written exactly once).
// ---------------------------------------------------------------------------
__global__ void row_offsets_kernel(const int* __restrict__ dst, int n_edge,
                                   int* __restrict__ rs, int n_dst) {
  int e = blockIdx.x * blockDim.x + threadIdx.x;
  if (e >= n_edge) return;
  int d = dst[e];
  int dprev = (e == 0) ? -1 : dst[e - 1];
  for (int i = dprev + 1; i <= d; ++i) rs[i] = e;
  if (e == n_edge - 1)
    for (int i = d + 1; i <= n_dst; ++i) rs[i] = n_edge;
}

// ---------------------------------------------------------------------------
// One-time W prep (RNE split): W[256][128] fp32 -> Wt_hi/Wt_lo[128][256] bf16,
// k permuted to MFMA slot order.
// ---------------------------------------------------------------------------
__global__ __launch_bounds__(256) void wt_prep_kernel(
    const float* __restrict__ W, unsigned short* __restrict__ WtHi,
    unsigned short* __restrict__ WtLo) {
  int tid = blockIdx.x * blockDim.x + threadIdx.x;
  if (tid >= D_IN * D_H) return;
  int n = tid & 127, k = tid >> 7;
  float x = W[(size_t)k * D_H + n];
  unsigned short h = f2bf(x);
  unsigned short l = f2bf(x - bf2f(h));
  int kk = k & 31, kbase = k & ~31;
  int pos = (kk < 16) ? ((kk >> 2) * 8 + (kk & 3))
                      : (((kk - 16) >> 2) * 8 + 4 + (kk & 3));
  WtHi[(size_t)n * D_IN + kbase + pos] = h;
  WtLo[(size_t)n * D_IN + kbase + pos] = l;
}

// ---------------------------------------------------------------------------
// Stage one K-step tile (A fp32 128x32 swizzled + B hi/lo 128x32 bf16) into
// LDS entirely via global_load_lds DMA. 8 gll instructions per wave.
// ---------------------------------------------------------------------------
__device__ __forceinline__ void stage_tile(
    const float* __restrict__ A, const unsigned short* __restrict__ WtHi,
    const unsigned short* __restrict__ WtLo, int m0, int M, int k0,
    int wave, int lane, float* Af, unsigned short* Bh, unsigned short* Bl) {
#pragma unroll
  for (int i = 0; i < 4; ++i) {
    int rloc = wave * 32 + i * 8 + (lane >> 3);
    int gr = m0 + rloc; if (gr >= M) gr = M - 1;       // clamp; rows never stored
    int u = (lane & 7) ^ (rloc & 7);
    const float* src = A + (size_t)gr * D_IN + k0 + u * 4;
    char* dstb = (char*)Af + (size_t)(wave * 32 + i * 8) * 128;  // wave-uniform
    __builtin_amdgcn_global_load_lds(
        (const __attribute__((address_space(1))) unsigned int*)src,
        (__attribute__((address_space(3))) unsigned int*)dstb, 16, 0, 0);
  }
#pragma unroll
  for (int i = 0; i < 2; ++i) {
    int row = wave * 32 + i * 16 + (lane >> 2);
    int ch = lane & 3;
    const unsigned short* srch = WtHi + (size_t)row * D_IN + k0 + ch * 8;
    char* dsth = (char*)Bh + (size_t)(wave * 32 + i * 16) * 64;
    __builtin_amdgcn_global_load_lds(
        (const __attribute__((address_space(1))) unsigned int*)srch,
        (__attribute__((address_space(3))) unsigned int*)dsth, 16, 0, 0);
    const unsigned short* srcl = WtLo + (size_t)row * D_IN + k0 + ch * 8;
    char* dstl = (char*)Bl + (size_t)(wave * 32 + i * 16) * 64;
    __builtin_amdgcn_global_load_lds(
        (const __attribute__((address_space(1))) unsigned int*)srcl,
        (__attribute__((address_space(3))) unsigned int*)dstl, 16, 0, 0);
  }
}

// ---------------------------------------------------------------------------
// FUSED projections + FUSED SCORES, now with COUNTED-VMCNT PIPELINE (r19):
// r13's loop used __syncthreads(), whose vmcnt(0) drain killed the prefetch
// every iteration (the tile-t+1 DMA just issued was force-completed). Now:
//   stage(t+1) -> s_waitcnt vmcnt(8) [tile t done, t+1 in flight]
//   -> sched_barrier(0) -> raw s_barrier -> compute(t) -> raw s_barrier
// Each wave waits its own 8 loads BEFORE the barrier, so at barrier exit all
// waves' tile-t loads are complete (B rows are cross-wave). Last iter: vmcnt(0).
// C/D layout (verified m89): col = lane&15, row = (lane>>4)*4 + reg.
// ---------------------------------------------------------------------------
__global__ __launch_bounds__(256) void gemm_fused_kernel(
    const float* __restrict__ Au, const float* __restrict__ Ai,
    const unsigned short* __restrict__ WtUHi, const unsigned short* __restrict__ WtULo,
    const unsigned short* __restrict__ WtIHi, const unsigned short* __restrict__ WtILo,
    const float* __restrict__ bu, const float* __restrict__ bi,
    const float* __restrict__ aUdst, const float* __restrict__ aUsrc,
    const float* __restrict__ aIdst,
    float* __restrict__ sUdst, float* __restrict__ sIsrc,
    float* __restrict__ sIdst,
    unsigned short* __restrict__ CiBf, int nbu) {
  __shared__ float Af[2][128 * 32];                     // 2 x 16KB
  __shared__ unsigned short Bhs[2][128 * 32];           // 2 x 8KB
  __shared__ unsigned short Bls[2][128 * 32];           // 2 x 8KB  (total 64KB)
  const bool isU = (int)blockIdx.x < nbu;
  const float* A = isU ? Au : Ai;
  const unsigned short* WtHi = isU ? WtUHi : WtIHi;
  const unsigned short* WtLo = isU ? WtULo : WtILo;
  const float* bias = isU ? bu : bi;
  const int M = isU ? N_USER : N_ITEM;
  const int m0 = (isU ? (int)blockIdx.x : (int)blockIdx.x - nbu) * 128;

  const int t = threadIdx.x;
  const int wave = t >> 6, lane = t & 63;
  const int l15 = lane & 15, kb = lane >> 4;

  f32x4 acc[2][8];
#pragma unroll
  for (int mf = 0; mf < 2; ++mf)
#pragma unroll
    for (int nf = 0; nf < 8; ++nf) acc[mf][nf] = (f32x4){0.f, 0.f, 0.f, 0.f};

  stage_tile(A, WtHi, WtLo, m0, M, 0, wave, lane, Af[0], Bhs[0], Bls[0]);

#pragma unroll
  for (int ts = 0; ts < 8; ++ts) {
    const int cur = ts & 1;
    if (ts + 1 < 8) {                                  // prefetch next tile
      stage_tile(A, WtHi, WtLo, m0, M, (ts + 1) * 32, wave, lane,
                 Af[cur ^ 1], Bhs[cur ^ 1], Bls[cur ^ 1]);
      asm volatile("s_waitcnt vmcnt(8)" ::: "memory"); // tile ts done; ts+1 in flight
    } else {
      asm volatile("s_waitcnt vmcnt(0)" ::: "memory"); // final tile: drain all
    }
    __builtin_amdgcn_sched_barrier(0);                 // rule #18 fence
    __builtin_amdgcn_s_barrier();                      // all waves' tile ts ready

    short8v ah[2], al[2];
#pragma unroll
    for (int mf = 0; mf < 2; ++mf) {
      int row = wave * 32 + mf * 16 + l15;
      int u0 = kb ^ (row & 7);
      int u1 = (kb + 4) ^ (row & 7);
      float4 f0 = *(const float4*)((const char*)Af[cur] + (size_t)row * 128 + u0 * 16);
      float4 f1 = *(const float4*)((const char*)Af[cur] + (size_t)row * 128 + u1 * 16);
      const float e[8] = {f0.x, f0.y, f0.z, f0.w, f1.x, f1.y, f1.z, f1.w};
#pragma unroll
      for (int j = 0; j < 8; ++j) {
        unsigned short h = f2bf(e[j]);
        ah[mf][j] = (short)h;
        al[mf][j] = (short)f2bf(e[j] - bf2f(h));
      }
    }
#pragma unroll
    for (int nf = 0; nf < 8; ++nf) {
      short8v bh = *(const short8v*)((const char*)Bhs[cur] + (size_t)(nf * 16 + l15) * 64 + kb * 16);
      short8v bl = *(const short8v*)((const char*)Bls[cur] + (size_t)(nf * 16 + l15) * 64 + kb * 16);
#pragma unroll
      for (int mf = 0; mf < 2; ++mf) {
        acc[mf][nf] = __builtin_amdgcn_mfma_f32_16x16x32_bf16(ah[mf], bh, acc[mf][nf], 0, 0, 0);
        acc[mf][nf] = __builtin_amdgcn_mfma_f32_16x16x32_bf16(ah[mf], bl, acc[mf][nf], 0, 0, 0);
        acc[mf][nf] = __builtin_amdgcn_mfma_f32_16x16x32_bf16(al[mf], bh, acc[mf][nf], 0, 0, 0);
      }
    }
    __builtin_amdgcn_s_barrier();   // readers done before buf reuse (no drain)
  }

  // ---- epilogue: bf16 C (item) + fused scores ----
  if (!isU) {
#pragma unroll
    for (int nf = 0; nf < 8; ++nf) {
      float b8 = bias[nf * 16 + l15];
#pragma unroll
      for (int mf = 0; mf < 2; ++mf) {
#pragma unroll
        for (int r = 0; r < 4; ++r) {
          int grow = m0 + wave * 32 + mf * 16 + kb * 4 + r;
          if (grow < M)
            CiBf[(size_t)grow * D_H + nf * 16 + l15] = f2bf(acc[mf][nf][r] + b8);
        }
      }
    }
  }
  const float* a0 = isU ? aUdst : aUsrc;
  float* s0 = isU ? sUdst : sIsrc;
#pragma unroll
  for (int h = 0; h < HEADS; ++h) {
    float a0v[8], bd0 = 0.f;
#pragma unroll
    for (int nf = 0; nf < 8; ++nf) {
      a0v[nf] = a0[h * D_H + nf * 16 + l15];
      bd0 = fmaf(bias[nf * 16 + l15], a0v[nf], bd0);
    }
#pragma unroll
    for (int mf = 0; mf < 2; ++mf) {
#pragma unroll
      for (int r = 0; r < 4; ++r) {
        float p = bd0;
#pragma unroll
        for (int nf = 0; nf < 8; ++nf) p = fmaf(acc[mf][nf][r], a0v[nf], p);
        p += __shfl_xor(p, 1); p += __shfl_xor(p, 2);
        p += __shfl_xor(p, 4); p += __shfl_xor(p, 8);
        int grow = m0 + wave * 32 + mf * 16 + kb * 4 + r;
        if (l15 == 0 && grow < M) s0[grow * HEADS + h] = p;
      }
    }
  }
  if (!isU) {
#pragma unroll
    for (int h = 0; h < HEADS; ++h) {
      float a1v[8], bd1 = 0.f;
#pragma unroll
      for (int nf = 0; nf < 8; ++nf) {
        a1v[nf] = aIdst[h * D_H + nf * 16 + l15];
        bd1 = fmaf(bias[nf * 16 + l15], a1v[nf], bd1);
      }
#pragma unroll
      for (int mf = 0; mf < 2; ++mf) {
#pragma unroll
        for (int r = 0; r < 4; ++r) {
          float p = bd1;
#pragma unroll
          for (int nf = 0; nf < 8; ++nf) p = fmaf(acc[mf][nf][r], a1v[nf], p);
          p += __shfl_xor(p, 1); p += __shfl_xor(p, 2);
          p += __shfl_xor(p, 4); p += __shfl_xor(p, 8);
          int grow = m0 + wave * 32 + mf * 16 + kb * 4 + r;
          if (l15 == 0 && grow < M) sIdst[grow * HEADS + h] = p;
        }
      }
    }
  }
}

// ---------------------------------------------------------------------------
// Weighted gather-sum with inline edge weights (r18-exact, measured 220.8).
// 2 dst/wave, bf16 gather rows; den lane-uniform (no reductions).
// ---------------------------------------------------------------------------
__global__ __launch_bounds__(256) void attend_sum_kernel(
    const unsigned short* __restrict__ h_src, const float* __restrict__ s_src,
    const float* __restrict__ s_dst, const int* __restrict__ src_idx,
    const int* __restrict__ rs, float* __restrict__ out,
    unsigned short* __restrict__ out_bf, int n_dst,
    const float* __restrict__ a_next, float* __restrict__ s_out) {
  int gw = (blockIdx.x * blockDim.x + threadIdx.x) >> 6;   // global wave id
  int lane = threadIdx.x & 63;
  int half = lane >> 5;
  int ll = lane & 31;                // dim group: dims [ll*4, ll*4+4)
  int wid = gw * 2 + half;           // this half's dst node
  if (wid >= n_dst) return;
  int e0 = rs[wid], e1 = rs[wid + 1];
  f32x4 sd = *(const f32x4*)&s_dst[(size_t)wid * HEADS];

#define EDGE_W(sv, wv) {                                                    \
    f32x4 v_ = sv + sd;                                                     \
    v_.x = (v_.x >= 0.f) ? v_.x : 0.2f * v_.x;                              \
    v_.y = (v_.y >= 0.f) ? v_.y : 0.2f * v_.y;                              \
    v_.z = (v_.z >= 0.f) ? v_.z : 0.2f * v_.z;                              \
    v_.w = (v_.w >= 0.f) ? v_.w : 0.2f * v_.w;                              \
    wv = (f32x4){__expf(v_.x), __expf(v_.y), __expf(v_.z), __expf(v_.w)};   \
  }

  f32x4 acc0 = {0, 0, 0, 0}, acc1 = acc0, acc2 = acc0, acc3 = acc0;
  f32x4 den = {0, 0, 0, 0};

  int base = e0;
  for (; base + 2 <= e1; base += 2) {
    int sA = src_idx[base], sB = src_idx[base + 1];
    ushort4 gA = *(const ushort4*)&h_src[(size_t)sA * D_H + ll * 4];
    ushort4 gB = *(const ushort4*)&h_src[(size_t)sB * D_H + ll * 4];
    f32x4 svA = *(const f32x4*)&s_src[(size_t)sA * HEADS];
    f32x4 svB = *(const f32x4*)&s_src[(size_t)sB * HEADS];
    f32x4 hA = {bf2f(gA.x), bf2f(gA.y), bf2f(gA.z), bf2f(gA.w)};
    f32x4 hB = {bf2f(gB.x), bf2f(gB.y), bf2f(gB.z), bf2f(gB.w)};
    f32x4 wA, wB;
    EDGE_W(svA, wA); EDGE_W(svB, wB);
    den += wA; den += wB;
    acc0 = __builtin_elementwise_fma(splat4(wA.x), hA, acc0);
    acc1 = __builtin_elementwise_fma(splat4(wA.y), hA, acc1);
    acc2 = __builtin_elementwise_fma(splat4(wA.z), hA, acc2);
    acc3 = __builtin_elementwise_fma(splat4(wA.w), hA, acc3);
    acc0 = __builtin_elementwise_fma(splat4(wB.x), hB, acc0);
    acc1 = __builtin_elementwise_fma(splat4(wB.y), hB, acc1);
    acc2 = __builtin_elementwise_fma(splat4(wB.z), hB, acc2);
    acc3 = __builtin_elementwise_fma(splat4(wB.w), hB, acc3);
  }
  if (base < e1) {
    int s = src_idx[base];
    ushort4 gv = *(const ushort4*)&h_src[(size_t)s * D_H + ll * 4];
    f32x4 sv = *(const f32x4*)&s_src[(size_t)s * HEADS];
    f32x4 hv = {bf2f(gv.x), bf2f(gv.y), bf2f(gv.z), bf2f(gv.w)};
    f32x4 wv;
    EDGE_W(sv, wv);
    den += wv;
    acc0 = __builtin_elementwise_fma(splat4(wv.x), hv, acc0);
    acc1 = __builtin_elementwise_fma(splat4(wv.y), hv, acc1);
    acc2 = __builtin_elementwise_fma(splat4(wv.z), hv, acc2);
    acc3 = __builtin_elementwise_fma(splat4(wv.w), hv, acc3);
  }
#undef EDGE_W

  float rA = den.x > 0.f ? __builtin_amdgcn_rcpf(den.x) : 0.f;
  float rB = den.y > 0.f ? __builtin_amdgcn_rcpf(den.y) : 0.f;
  float rC = den.z > 0.f ? __builtin_amdgcn_rcpf(den.z) : 0.f;
  float rD = den.w > 0.f ? __builtin_amdgcn_rcpf(den.w) : 0.f;
  acc0 *= splat4(rA); acc1 *= splat4(rB); acc2 *= splat4(rC); acc3 *= splat4(rD);
#define ELU4(a) \
  a.x = (a.x > 0.f) ? a.x : (__expf(a.x) - 1.f); \
  a.y = (a.y > 0.f) ? a.y : (__expf(a.y) - 1.f); \
  a.z = (a.z > 0.f) ? a.z : (__expf(a.z) - 1.f); \
  a.w = (a.w > 0.f) ? a.w : (__expf(a.w) - 1.f);
  ELU4(acc0) ELU4(acc1) ELU4(acc2) ELU4(acc3)
#undef ELU4
  f32x4 o = (acc0 + acc1 + acc2 + acc3) * splat4(0.25f);
  *(f32x4*)&out[(size_t)wid * D_H + ll * 4] = o;
  if (out_bf) {
    ushort4 ob = {f2bf(o.x), f2bf(o.y), f2bf(o.z), f2bf(o.w)};
    *(ushort4*)&out_bf[(size_t)wid * D_H + ll * 4] = ob;
  }

  if (s_out) {
#pragma unroll
    for (int h = 0; h < HEADS; ++h) {
      const float* ah = &a_next[h * D_H + ll * 4];
      float p = o.x * ah[0] + o.y * ah[1] + o.z * ah[2] + o.w * ah[3];
#pragma unroll
      for (int off = 16; off; off >>= 1) p += __shfl_xor(p, off);
      if (ll == 0) s_out[wid * HEADS + h] = p;
    }
  }
}

// ---------------------------------------------------------------------------
extern "C" void kernel_launch(void* const* d_in, const int* in_sizes, int n_in,
                              void* d_out, int out_size, void* d_ws, size_t ws_size,
                              hipStream_t stream) {
  const float* h_user     = (const float*)d_in[0];
  const float* h_item     = (const float*)d_in[1];
  const float* w_user     = (const float*)d_in[2];
  const float* b_user     = (const float*)d_in[3];
  const float* w_item     = (const float*)d_in[4];
  const float* b_item     = (const float*)d_in[5];
  const float* a_user_src = (const float*)d_in[6];
  const float* a_user_dst = (const float*)d_in[7];
  const float* a_item_src = (const float*)d_in[8];
  const float* a_item_dst = (const float*)d_in[9];
  const int* i2u_src = (const int*)d_in[10];
  const int* i2u_dst = (const int*)d_in[11];
  const int* u2i_src = (const int*)d_in[12];
  const int* u2i_dst = (const int*)d_in[13];

  float* out_user = (float*)d_out;                       // hu_new (N_USER,128)
  float* out_item = out_user + (size_t)N_USER * D_H;     // hi_new (N_ITEM,128)

  // workspace layout
  float* base_f  = (float*)d_ws;
  unsigned short* ou_bf = (unsigned short*)base_f;       // (N_USER,128) bf16 25.6MB
  float* s_i_src = (float*)(ou_bf + (size_t)N_USER * D_H);  // (N_ITEM,4)
  float* s_i_dst = s_i_src + (size_t)N_ITEM * HEADS;     // (N_ITEM,4)
  float* s_u_dst = s_i_dst + (size_t)N_ITEM * HEADS;     // (N_USER,4)
  float* s_un    = s_u_dst + (size_t)N_USER * HEADS;     // (N_USER,4)
  int* user_rs = (int*)(s_un + (size_t)N_USER * HEADS);  // N_USER+1
  int* item_rs = user_rs + (N_USER + 1);                 // N_ITEM+1
  unsigned short* wtu_hi = (unsigned short*)
      (((uintptr_t)(item_rs + N_ITEM + 1) + 15) & ~(uintptr_t)15);
  unsigned short* wtu_lo = wtu_hi + (size_t)D_IN * D_H;
  unsigned short* wti_hi = wtu_lo + (size_t)D_IN * D_H;
  unsigned short* wti_lo = wti_hi + (size_t)D_IN * D_H;
  unsigned short* hi_bf  = wti_lo + (size_t)D_IN * D_H;  // (N_ITEM,128) bf16 12.8MB

  // CSR offsets (edge-parallel run writes)
  hipLaunchKernelGGL(row_offsets_kernel, dim3((N_EDGE + 255) / 256), dim3(256), 0,
                     stream, i2u_dst, N_EDGE, user_rs, N_USER);
  hipLaunchKernelGGL(row_offsets_kernel, dim3((N_EDGE + 255) / 256), dim3(256), 0,
                     stream, u2i_dst, N_EDGE, item_rs, N_ITEM);

  // W prep + FUSED projections+scores (one dispatch, 1173 blocks)
  hipLaunchKernelGGL(wt_prep_kernel, dim3(D_IN * D_H / 256), dim3(256), 0, stream,
                     w_user, wtu_hi, wtu_lo);
  hipLaunchKernelGGL(wt_prep_kernel, dim3(D_IN * D_H / 256), dim3(256), 0, stream,
                     w_item, wti_hi, wti_lo);
  const int nbu = (N_USER + 127) / 128;                  // 782
  const int nbi = (N_ITEM + 127) / 128;                  // 391
  hipLaunchKernelGGL(gemm_fused_kernel, dim3(nbu + nbi), dim3(256), 0, stream,
                     h_user, h_item, wtu_hi, wtu_lo, wti_hi, wti_lo,
                     b_user, b_item,
                     a_user_dst, a_user_src, a_item_dst,
                     s_u_dst, s_i_src, s_i_dst, hi_bf, nbu);

  // ---- layer 1: items -> users ----  (bf16 gather; inline edge weights)
  hipLaunchKernelGGL(attend_sum_kernel, dim3((N_USER + 7) / 8), dim3(256), 0, stream,
                     hi_bf, s_i_src, s_u_dst, i2u_src, user_rs,
                     out_user, ou_bf, N_USER, a_item_src, s_un);

  // ---- layer 2: updated users -> items ----
  hipLaunchKernelGGL(attend_sum_kernel, dim3((N_ITEM + 7) / 8), dim3(256), 0, stream,
                     ou_bf, s_un, s_i_dst, u2i_src, item_rs,
                     out_item, (unsigned short*)nullptr, N_ITEM,
                     (const float*)nullptr, (float*)nullptr);
}

// Round 20
// 205.410 us; speedup vs baseline: 1.5431x; 1.0555x over previous
//
#include <hip/hip_runtime.h>
#include <math.h>

#define N_USER 100000
#define N_ITEM 50000
#define N_EDGE 800000
#define D_IN 256
#define D_H 128
#define HEADS 4

typedef __attribute__((ext_vector_type(8))) _Float16 half8v;  // 8 f16 (4 VGPR)
typedef __attribute__((ext_vector_type(4))) float f32x4;      // 4 fp32

__device__ __forceinline__ unsigned short f2bf(float x) {    // RNE f32->bf16
  unsigned u = __float_as_uint(x);
  return (unsigned short)((u + 0x7FFFu + ((u >> 16) & 1u)) >> 16);
}
__device__ __forceinline__ float bf2f(unsigned short h) {
  return __uint_as_float((unsigned)h << 16);
}
__device__ __forceinline__ f32x4 splat4(float x) { return (f32x4){x, x, x, x}; }

// ---------------------------------------------------------------------------
// CSR row offsets, edge-parallel run writes (each rs[i] written exactly once).
// ---------------------------------------------------------------------------
__global__ void row_offsets_kernel(const int* __restrict__ dst, int n_edge,
                                   int* __restrict__ rs, int n_dst) {
  int e = blockIdx.x * blockDim.x + threadIdx.x;
  if (e >= n_edge) return;
  int d = dst[e];
  int dprev = (e == 0) ? -1 : dst[e - 1];
  for (int i = dprev + 1; i <= d; ++i) rs[i] = e;
  if (e == n_edge - 1)
    for (int i = d + 1; i <= n_dst; ++i) rs[i] = n_edge;
}

// ---------------------------------------------------------------------------
// One-time W prep: W[256][128] fp32 -> Wt[128][256] fp16, k permuted to MFMA
// slot order: pos(k) s.t. slot (kb,j) holds k = kb*4 + (j&3) + 16*(j>>2).
// fp16 ok: |W| <~ 0.3 (N(0,1/16)); per-element rel err 2^-11.
// ---------------------------------------------------------------------------
__global__ __launch_bounds__(256) void wt_prep_kernel(
    const float* __restrict__ W, _Float16* __restrict__ Wt) {
  int tid = blockIdx.x * blockDim.x + threadIdx.x;
  if (tid >= D_IN * D_H) return;
  int n = tid & 127, k = tid >> 7;
  float x = W[(size_t)k * D_H + n];
  int kk = k & 31, kbase = k & ~31;
  int pos = (kk < 16) ? ((kk >> 2) * 8 + (kk & 3))
                      : (((kk - 16) >> 2) * 8 + 4 + (kk & 3));
  Wt[(size_t)n * D_IN + kbase + pos] = (_Float16)x;
}

// ---------------------------------------------------------------------------
// Stage one K-step tile (A fp32 128x32 swizzled + B fp16 128x32) into LDS
// entirely via global_load_lds DMA. 6 gll instructions per wave.
// ---------------------------------------------------------------------------
__device__ __forceinline__ void stage_tile(
    const float* __restrict__ A, const _Float16* __restrict__ Wt,
    int m0, int M, int k0, int wave, int lane, float* Af, _Float16* Bf) {
#pragma unroll
  for (int i = 0; i < 4; ++i) {
    int rloc = wave * 32 + i * 8 + (lane >> 3);
    int gr = m0 + rloc; if (gr >= M) gr = M - 1;       // clamp; rows never stored
    int u = (lane & 7) ^ (rloc & 7);
    const float* src = A + (size_t)gr * D_IN + k0 + u * 4;
    char* dstb = (char*)Af + (size_t)(wave * 32 + i * 8) * 128;  // wave-uniform
    __builtin_amdgcn_global_load_lds(
        (const __attribute__((address_space(1))) unsigned int*)src,
        (__attribute__((address_space(3))) unsigned int*)dstb, 16, 0, 0);
  }
  // B: fp16 row = 64B; lane l -> row base+(l>>2), 16B unit l&3 (linear).
#pragma unroll
  for (int i = 0; i < 2; ++i) {
    int row = wave * 32 + i * 16 + (lane >> 2);
    int ch = lane & 3;
    const _Float16* srch = Wt + (size_t)row * D_IN + k0 + ch * 8;
    char* dsth = (char*)Bf + (size_t)(wave * 32 + i * 16) * 64;
    __builtin_amdgcn_global_load_lds(
        (const __attribute__((address_space(1))) unsigned int*)srch,
        (__attribute__((address_space(3))) unsigned int*)dsth, 16, 0, 0);
  }
}

// ---------------------------------------------------------------------------
// FUSED projections + FUSED SCORES, SINGLE-MFMA FP16 (r20): the 3-term
// split-bf16 path (48 MFMA/K-step) was 3x the needed matrix work; fp16's
// 2^-11 rel error is far below the bf16-row error already in absmax. Now
// 16 MFMA/K-step, one B array, 6 gll/wave/K-step, LDS 48KB -> 3 blocks/CU.
// Counted-vmcnt pipeline (r19) retained: stage(t+1) -> vmcnt(6) -> barrier
// -> compute(t) -> barrier. C/D layout: col=lane&15, row=(lane>>4)*4+reg.
// ---------------------------------------------------------------------------
__global__ __launch_bounds__(256) void gemm_fused_kernel(
    const float* __restrict__ Au, const float* __restrict__ Ai,
    const _Float16* __restrict__ WtU, const _Float16* __restrict__ WtI,
    const float* __restrict__ bu, const float* __restrict__ bi,
    const float* __restrict__ aUdst, const float* __restrict__ aUsrc,
    const float* __restrict__ aIdst,
    float* __restrict__ sUdst, float* __restrict__ sIsrc,
    float* __restrict__ sIdst,
    unsigned short* __restrict__ CiBf, int nbu) {
  __shared__ float Af[2][128 * 32];                     // 2 x 16KB
  __shared__ _Float16 Bfs[2][128 * 32];                 // 2 x 8KB  (total 48KB)
  const bool isU = (int)blockIdx.x < nbu;
  const float* A = isU ? Au : Ai;
  const _Float16* Wt = isU ? WtU : WtI;
  const float* bias = isU ? bu : bi;
  const int M = isU ? N_USER : N_ITEM;
  const int m0 = (isU ? (int)blockIdx.x : (int)blockIdx.x - nbu) * 128;

  const int t = threadIdx.x;
  const int wave = t >> 6, lane = t & 63;
  const int l15 = lane & 15, kb = lane >> 4;

  f32x4 acc[2][8];
#pragma unroll
  for (int mf = 0; mf < 2; ++mf)
#pragma unroll
    for (int nf = 0; nf < 8; ++nf) acc[mf][nf] = (f32x4){0.f, 0.f, 0.f, 0.f};

  stage_tile(A, Wt, m0, M, 0, wave, lane, Af[0], Bfs[0]);

#pragma unroll
  for (int ts = 0; ts < 8; ++ts) {
    const int cur = ts & 1;
    if (ts + 1 < 8) {                                  // prefetch next tile
      stage_tile(A, Wt, m0, M, (ts + 1) * 32, wave, lane,
                 Af[cur ^ 1], Bfs[cur ^ 1]);
      asm volatile("s_waitcnt vmcnt(6)" ::: "memory"); // tile ts done; ts+1 in flight
    } else {
      asm volatile("s_waitcnt vmcnt(0)" ::: "memory"); // final tile: drain all
    }
    __builtin_amdgcn_sched_barrier(0);                 // rule #18 fence
    __builtin_amdgcn_s_barrier();                      // all waves' tile ts ready

    half8v ah[2];
#pragma unroll
    for (int mf = 0; mf < 2; ++mf) {
      int row = wave * 32 + mf * 16 + l15;
      int u0 = kb ^ (row & 7);
      int u1 = (kb + 4) ^ (row & 7);
      float4 f0 = *(const float4*)((const char*)Af[cur] + (size_t)row * 128 + u0 * 16);
      float4 f1 = *(const float4*)((const char*)Af[cur] + (size_t)row * 128 + u1 * 16);
      const float e[8] = {f0.x, f0.y, f0.z, f0.w, f1.x, f1.y, f1.z, f1.w};
#pragma unroll
      for (int j = 0; j < 8; ++j) ah[mf][j] = (_Float16)e[j];
    }
#pragma unroll
    for (int nf = 0; nf < 8; ++nf) {
      half8v bh = *(const half8v*)((const char*)Bfs[cur] + (size_t)(nf * 16 + l15) * 64 + kb * 16);
#pragma unroll
      for (int mf = 0; mf < 2; ++mf)
        acc[mf][nf] = __builtin_amdgcn_mfma_f32_16x16x32_f16(ah[mf], bh, acc[mf][nf], 0, 0, 0);
    }
    __builtin_amdgcn_s_barrier();   // readers done before buf reuse (no drain)
  }

  // ---- epilogue: bf16 C (item) + fused scores ----
  if (!isU) {
#pragma unroll
    for (int nf = 0; nf < 8; ++nf) {
      float b8 = bias[nf * 16 + l15];
#pragma unroll
      for (int mf = 0; mf < 2; ++mf) {
#pragma unroll
        for (int r = 0; r < 4; ++r) {
          int grow = m0 + wave * 32 + mf * 16 + kb * 4 + r;
          if (grow < M)
            CiBf[(size_t)grow * D_H + nf * 16 + l15] = f2bf(acc[mf][nf][r] + b8);
        }
      }
    }
  }
  const float* a0 = isU ? aUdst : aUsrc;
  float* s0 = isU ? sUdst : sIsrc;
#pragma unroll
  for (int h = 0; h < HEADS; ++h) {
    float a0v[8], bd0 = 0.f;
#pragma unroll
    for (int nf = 0; nf < 8; ++nf) {
      a0v[nf] = a0[h * D_H + nf * 16 + l15];
      bd0 = fmaf(bias[nf * 16 + l15], a0v[nf], bd0);
    }
#pragma unroll
    for (int mf = 0; mf < 2; ++mf) {
#pragma unroll
      for (int r = 0; r < 4; ++r) {
        float p = bd0;
#pragma unroll
        for (int nf = 0; nf < 8; ++nf) p = fmaf(acc[mf][nf][r], a0v[nf], p);
        p += __shfl_xor(p, 1); p += __shfl_xor(p, 2);
        p += __shfl_xor(p, 4); p += __shfl_xor(p, 8);
        int grow = m0 + wave * 32 + mf * 16 + kb * 4 + r;
        if (l15 == 0 && grow < M) s0[grow * HEADS + h] = p;
      }
    }
  }
  if (!isU) {
#pragma unroll
    for (int h = 0; h < HEADS; ++h) {
      float a1v[8], bd1 = 0.f;
#pragma unroll
      for (int nf = 0; nf < 8; ++nf) {
        a1v[nf] = aIdst[h * D_H + nf * 16 + l15];
        bd1 = fmaf(bias[nf * 16 + l15], a1v[nf], bd1);
      }
#pragma unroll
      for (int mf = 0; mf < 2; ++mf) {
#pragma unroll
        for (int r = 0; r < 4; ++r) {
          float p = bd1;
#pragma unroll
          for (int nf = 0; nf < 8; ++nf) p = fmaf(acc[mf][nf][r], a1v[nf], p);
          p += __shfl_xor(p, 1); p += __shfl_xor(p, 2);
          p += __shfl_xor(p, 4); p += __shfl_xor(p, 8);
          int grow = m0 + wave * 32 + mf * 16 + kb * 4 + r;
          if (l15 == 0 && grow < M) sIdst[grow * HEADS + h] = p;
        }
      }
    }
  }
}

// ---------------------------------------------------------------------------
// Weighted gather-sum with inline edge weights (r18-exact).
// 2 dst/wave, bf16 gather rows; den lane-uniform (no reductions).
// ---------------------------------------------------------------------------
__global__ __launch_bounds__(256) void attend_sum_kernel(
    const unsigned short* __restrict__ h_src, const float* __restrict__ s_src,
    const float* __restrict__ s_dst, const int* __restrict__ src_idx,
    const int* __restrict__ rs, float* __restrict__ out,
    unsigned short* __restrict__ out_bf, int n_dst,
    const float* __restrict__ a_next, float* __restrict__ s_out) {
  int gw = (blockIdx.x * blockDim.x + threadIdx.x) >> 6;   // global wave id
  int lane = threadIdx.x & 63;
  int half = lane >> 5;
  int ll = lane & 31;                // dim group: dims [ll*4, ll*4+4)
  int wid = gw * 2 + half;           // this half's dst node
  if (wid >= n_dst) return;
  int e0 = rs[wid], e1 = rs[wid + 1];
  f32x4 sd = *(const f32x4*)&s_dst[(size_t)wid * HEADS];

#define EDGE_W(sv, wv) {                                                    \
    f32x4 v_ = sv + sd;                                                     \
    v_.x = (v_.x >= 0.f) ? v_.x : 0.2f * v_.x;                              \
    v_.y = (v_.y >= 0.f) ? v_.y : 0.2f * v_.y;                              \
    v_.z = (v_.z >= 0.f) ? v_.z : 0.2f * v_.z;                              \
    v_.w = (v_.w >= 0.f) ? v_.w : 0.2f * v_.w;                              \
    wv = (f32x4){__expf(v_.x), __expf(v_.y), __expf(v_.z), __expf(v_.w)};   \
  }

  f32x4 acc0 = {0, 0, 0, 0}, acc1 = acc0, acc2 = acc0, acc3 = acc0;
  f32x4 den = {0, 0, 0, 0};

  int base = e0;
  for (; base + 2 <= e1; base += 2) {
    int sA = src_idx[base], sB = src_idx[base + 1];
    ushort4 gA = *(const ushort4*)&h_src[(size_t)sA * D_H + ll * 4];
    ushort4 gB = *(const ushort4*)&h_src[(size_t)sB * D_H + ll * 4];
    f32x4 svA = *(const f32x4*)&s_src[(size_t)sA * HEADS];
    f32x4 svB = *(const f32x4*)&s_src[(size_t)sB * HEADS];
    f32x4 hA = {bf2f(gA.x), bf2f(gA.y), bf2f(gA.z), bf2f(gA.w)};
    f32x4 hB = {bf2f(gB.x), bf2f(gB.y), bf2f(gB.z), bf2f(gB.w)};
    f32x4 wA, wB;
    EDGE_W(svA, wA); EDGE_W(svB, wB);
    den += wA; den += wB;
    acc0 = __builtin_elementwise_fma(splat4(wA.x), hA, acc0);
    acc1 = __builtin_elementwise_fma(splat4(wA.y), hA, acc1);
    acc2 = __builtin_elementwise_fma(splat4(wA.z), hA, acc2);
    acc3 = __builtin_elementwise_fma(splat4(wA.w), hA, acc3);
    acc0 = __builtin_elementwise_fma(splat4(wB.x), hB, acc0);
    acc1 = __builtin_elementwise_fma(splat4(wB.y), hB, acc1);
    acc2 = __builtin_elementwise_fma(splat4(wB.z), hB, acc2);
    acc3 = __builtin_elementwise_fma(splat4(wB.w), hB, acc3);
  }
  if (base < e1) {
    int s = src_idx[base];
    ushort4 gv = *(const ushort4*)&h_src[(size_t)s * D_H + ll * 4];
    f32x4 sv = *(const f32x4*)&s_src[(size_t)s * HEADS];
    f32x4 hv = {bf2f(gv.x), bf2f(gv.y), bf2f(gv.z), bf2f(gv.w)};
    f32x4 wv;
    EDGE_W(sv, wv);
    den += wv;
    acc0 = __builtin_elementwise_fma(splat4(wv.x), hv, acc0);
    acc1 = __builtin_elementwise_fma(splat4(wv.y), hv, acc1);
    acc2 = __builtin_elementwise_fma(splat4(wv.z), hv, acc2);
    acc3 = __builtin_elementwise_fma(splat4(wv.w), hv, acc3);
  }
#undef EDGE_W

  float rA = den.x > 0.f ? __builtin_amdgcn_rcpf(den.x) : 0.f;
  float rB = den.y > 0.f ? __builtin_amdgcn_rcpf(den.y) : 0.f;
  float rC = den.z > 0.f ? __builtin_amdgcn_rcpf(den.z) : 0.f;
  float rD = den.w > 0.f ? __builtin_amdgcn_rcpf(den.w) : 0.f;
  acc0 *= splat4(rA); acc1 *= splat4(rB); acc2 *= splat4(rC); acc3 *= splat4(rD);
#define ELU4(a) \
  a.x = (a.x > 0.f) ? a.x : (__expf(a.x) - 1.f); \
  a.y = (a.y > 0.f) ? a.y : (__expf(a.y) - 1.f); \
  a.z = (a.z > 0.f) ? a.z : (__expf(a.z) - 1.f); \
  a.w = (a.w > 0.f) ? a.w : (__expf(a.w) - 1.f);
  ELU4(acc0) ELU4(acc1) ELU4(acc2) ELU4(acc3)
#undef ELU4
  f32x4 o = (acc0 + acc1 + acc2 + acc3) * splat4(0.25f);
  *(f32x4*)&out[(size_t)wid * D_H + ll * 4] = o;
  if (out_bf) {
    ushort4 ob = {f2bf(o.x), f2bf(o.y), f2bf(o.z), f2bf(o.w)};
    *(ushort4*)&out_bf[(size_t)wid * D_H + ll * 4] = ob;
  }

  if (s_out) {
#pragma unroll
    for (int h = 0; h < HEADS; ++h) {
      const float* ah = &a_next[h * D_H + ll * 4];
      float p = o.x * ah[0] + o.y * ah[1] + o.z * ah[2] + o.w * ah[3];
#pragma unroll
      for (int off = 16; off; off >>= 1) p += __shfl_xor(p, off);
      if (ll == 0) s_out[wid * HEADS + h] = p;
    }
  }
}

// ---------------------------------------------------------------------------
extern "C" void kernel_launch(void* const* d_in, const int* in_sizes, int n_in,
                              void* d_out, int out_size, void* d_ws, size_t ws_size,
                              hipStream_t stream) {
  const float* h_user     = (const float*)d_in[0];
  const float* h_item     = (const float*)d_in[1];
  const float* w_user     = (const float*)d_in[2];
  const float* b_user     = (const float*)d_in[3];
  const float* w_item     = (const float*)d_in[4];
  const float* b_item     = (const float*)d_in[5];
  const float* a_user_src = (const float*)d_in[6];
  const float* a_user_dst = (const float*)d_in[7];
  const float* a_item_src = (const float*)d_in[8];
  const float* a_item_dst = (const float*)d_in[9];
  const int* i2u_src = (const int*)d_in[10];
  const int* i2u_dst = (const int*)d_in[11];
  const int* u2i_src = (const int*)d_in[12];
  const int* u2i_dst = (const int*)d_in[13];

  float* out_user = (float*)d_out;                       // hu_new (N_USER,128)
  float* out_item = out_user + (size_t)N_USER * D_H;     // hi_new (N_ITEM,128)

  // workspace layout
  float* base_f  = (float*)d_ws;
  unsigned short* ou_bf = (unsigned short*)base_f;       // (N_USER,128) bf16 25.6MB
  float* s_i_src = (float*)(ou_bf + (size_t)N_USER * D_H);  // (N_ITEM,4)
  float* s_i_dst = s_i_src + (size_t)N_ITEM * HEADS;     // (N_ITEM,4)
  float* s_u_dst = s_i_dst + (size_t)N_ITEM * HEADS;     // (N_USER,4)
  float* s_un    = s_u_dst + (size_t)N_USER * HEADS;     // (N_USER,4)
  int* user_rs = (int*)(s_un + (size_t)N_USER * HEADS);  // N_USER+1
  int* item_rs = user_rs + (N_USER + 1);                 // N_ITEM+1
  _Float16* wtu = (_Float16*)
      (((uintptr_t)(item_rs + N_ITEM + 1) + 15) & ~(uintptr_t)15);
  _Float16* wti = wtu + (size_t)D_IN * D_H;              // 64KB each
  unsigned short* hi_bf = (unsigned short*)(wti + (size_t)D_IN * D_H);  // 12.8MB

  // CSR offsets (edge-parallel run writes)
  hipLaunchKernelGGL(row_offsets_kernel, dim3((N_EDGE + 255) / 256), dim3(256), 0,
                     stream, i2u_dst, N_EDGE, user_rs, N_USER);
  hipLaunchKernelGGL(row_offsets_kernel, dim3((N_EDGE + 255) / 256), dim3(256), 0,
                     stream, u2i_dst, N_EDGE, item_rs, N_ITEM);

  // W prep + FUSED fp16 projections+scores (one dispatch, 1173 blocks)
  hipLaunchKernelGGL(wt_prep_kernel, dim3(D_IN * D_H / 256), dim3(256), 0, stream,
                     w_user, wtu);
  hipLaunchKernelGGL(wt_prep_kernel, dim3(D_IN * D_H / 256), dim3(256), 0, stream,
                     w_item, wti);
  const int nbu = (N_USER + 127) / 128;                  // 782
  const int nbi = (N_ITEM + 127) / 128;                  // 391
  hipLaunchKernelGGL(gemm_fused_kernel, dim3(nbu + nbi), dim3(256), 0, stream,
                     h_user, h_item, wtu, wti, b_user, b_item,
                     a_user_dst, a_user_src, a_item_dst,
                     s_u_dst, s_i_src, s_i_dst, hi_bf, nbu);

  // ---- layer 1: items -> users ----  (bf16 gather; inline edge weights)
  hipLaunchKernelGGL(attend_sum_kernel, dim3((N_USER + 7) / 8), dim3(256), 0, stream,
                     hi_bf, s_i_src, s_u_dst, i2u_src, user_rs,
                     out_user, ou_bf, N_USER, a_item_src, s_un);

  // ---- layer 2: updated users -> items ----
  hipLaunchKernelGGL(attend_sum_kernel, dim3((N_ITEM + 7) / 8), dim3(256), 0, stream,
                     ou_bf, s_un, s_i_dst, u2i_src, item_rs,
                     out_item, (unsigned short*)nullptr, N_ITEM,
                     (const float*)nullptr, (float*)nullptr);
}

// Round 21
// 205.118 us; speedup vs baseline: 1.5453x; 1.0014x over previous
//
#include <hip/hip_runtime.h>
#include <math.h>

#define N_USER 100000
#define N_ITEM 50000
#define N_EDGE 800000
#define D_IN 256
#define D_H 128
#define HEADS 4

typedef __attribute__((ext_vector_type(8))) _Float16 half8v;  // 8 f16 (4 VGPR)
typedef __attribute__((ext_vector_type(4))) float f32x4;      // 4 fp32

__device__ __forceinline__ unsigned short f2bf(float x) {    // RNE f32->bf16
  unsigned u = __float_as_uint(x);
  return (unsigned short)((u + 0x7FFFu + ((u >> 16) & 1u)) >> 16);
}
__device__ __forceinline__ float bf2f(unsigned short h) {
  return __uint_as_float((unsigned)h << 16);
}
__device__ __forceinline__ f32x4 splat4(float x) { return (f32x4){x, x, x, x}; }

// ---------------------------------------------------------------------------
// CSR row offsets, edge-parallel run writes (each rs[i] written exactly once).
// ---------------------------------------------------------------------------
__global__ void row_offsets_kernel(const int* __restrict__ dst, int n_edge,
                                   int* __restrict__ rs, int n_dst) {
  int e = blockIdx.x * blockDim.x + threadIdx.x;
  if (e >= n_edge) return;
  int d = dst[e];
  int dprev = (e == 0) ? -1 : dst[e - 1];
  for (int i = dprev + 1; i <= d; ++i) rs[i] = e;
  if (e == n_edge - 1)
    for (int i = d + 1; i <= n_dst; ++i) rs[i] = n_edge;
}

// ---------------------------------------------------------------------------
// One-time W prep: W[256][128] fp32 -> Wt[128][256] fp16, k permuted to MFMA
// slot order: pos(k) s.t. slot (kb,j) holds k = kb*4 + (j&3) + 16*(j>>2).
// ---------------------------------------------------------------------------
__global__ __launch_bounds__(256) void wt_prep_kernel(
    const float* __restrict__ W, _Float16* __restrict__ Wt) {
  int tid = blockIdx.x * blockDim.x + threadIdx.x;
  if (tid >= D_IN * D_H) return;
  int n = tid & 127, k = tid >> 7;
  float x = W[(size_t)k * D_H + n];
  int kk = k & 31, kbase = k & ~31;
  int pos = (kk < 16) ? ((kk >> 2) * 8 + (kk & 3))
                      : (((kk - 16) >> 2) * 8 + 4 + (kk & 3));
  Wt[(size_t)n * D_IN + kbase + pos] = (_Float16)x;
}

// ---------------------------------------------------------------------------
// Stage one K-step tile (A fp32 128x32 swizzled + B fp16 128x32) into LDS
// entirely via global_load_lds DMA. 6 gll instructions per wave.
// ---------------------------------------------------------------------------
__device__ __forceinline__ void stage_tile(
    const float* __restrict__ A, const _Float16* __restrict__ Wt,
    int m0, int M, int k0, int wave, int lane, float* Af, _Float16* Bf) {
#pragma unroll
  for (int i = 0; i < 4; ++i) {
    int rloc = wave * 32 + i * 8 + (lane >> 3);
    int gr = m0 + rloc; if (gr >= M) gr = M - 1;       // clamp; rows never stored
    int u = (lane & 7) ^ (rloc & 7);
    const float* src = A + (size_t)gr * D_IN + k0 + u * 4;
    char* dstb = (char*)Af + (size_t)(wave * 32 + i * 8) * 128;  // wave-uniform
    __builtin_amdgcn_global_load_lds(
        (const __attribute__((address_space(1))) unsigned int*)src,
        (__attribute__((address_space(3))) unsigned int*)dstb, 16, 0, 0);
  }
  // B: fp16 row = 64B; lane l -> row base+(l>>2), 16B unit l&3 (linear).
#pragma unroll
  for (int i = 0; i < 2; ++i) {
    int row = wave * 32 + i * 16 + (lane >> 2);
    int ch = lane & 3;
    const _Float16* srch = Wt + (size_t)row * D_IN + k0 + ch * 8;
    char* dsth = (char*)Bf + (size_t)(wave * 32 + i * 16) * 64;
    __builtin_amdgcn_global_load_lds(
        (const __attribute__((address_space(1))) unsigned int*)srch,
        (__attribute__((address_space(3))) unsigned int*)dsth, 16, 0, 0);
  }
}

// ---------------------------------------------------------------------------
// FUSED fp16 projections + FUSED SCORES, PIPELINE DEPTH 2 (r21): r20 showed
// the GEMM moves ~93MB at only ~1000 GB/s with ~6 waves/CU each holding ONE
// tile's 6 DMA loads in flight -> load-concurrency-bound. Triple-buffer LDS
// (3 x 24KB = 72KB); steady state: stage(t+2) issued, wait vmcnt(12) (t's 6
// done; t+1/t+2's 12 airborne) -> barrier -> compute(t) -> barrier. Doubles
// per-wave MLP at the same occupancy. C/D: col=lane&15, row=(lane>>4)*4+reg.
// ---------------------------------------------------------------------------
__global__ __launch_bounds__(256) void gemm_fused_kernel(
    const float* __restrict__ Au, const float* __restrict__ Ai,
    const _Float16* __restrict__ WtU, const _Float16* __restrict__ WtI,
    const float* __restrict__ bu, const float* __restrict__ bi,
    const float* __restrict__ aUdst, const float* __restrict__ aUsrc,
    const float* __restrict__ aIdst,
    float* __restrict__ sUdst, float* __restrict__ sIsrc,
    float* __restrict__ sIdst,
    unsigned short* __restrict__ CiBf, int nbu) {
  __shared__ float Af[3][128 * 32];                     // 3 x 16KB
  __shared__ _Float16 Bfs[3][128 * 32];                 // 3 x 8KB  (total 72KB)
  const bool isU = (int)blockIdx.x < nbu;
  const float* A = isU ? Au : Ai;
  const _Float16* Wt = isU ? WtU : WtI;
  const float* bias = isU ? bu : bi;
  const int M = isU ? N_USER : N_ITEM;
  const int m0 = (isU ? (int)blockIdx.x : (int)blockIdx.x - nbu) * 128;

  const int t = threadIdx.x;
  const int wave = t >> 6, lane = t & 63;
  const int l15 = lane & 15, kb = lane >> 4;

  f32x4 acc[2][8];
#pragma unroll
  for (int mf = 0; mf < 2; ++mf)
#pragma unroll
    for (int nf = 0; nf < 8; ++nf) acc[mf][nf] = (f32x4){0.f, 0.f, 0.f, 0.f};

  stage_tile(A, Wt, m0, M, 0, wave, lane, Af[0], Bfs[0]);
  stage_tile(A, Wt, m0, M, 32, wave, lane, Af[1], Bfs[1]);

#pragma unroll
  for (int ts = 0; ts < 8; ++ts) {
    const int cur = ts % 3;
    if (ts + 2 < 8) {                                  // prefetch tile ts+2
      stage_tile(A, Wt, m0, M, (ts + 2) * 32, wave, lane,
                 Af[(ts + 2) % 3], Bfs[(ts + 2) % 3]);
      asm volatile("s_waitcnt vmcnt(12)" ::: "memory"); // ts done; ts+1,ts+2 fly
    } else if (ts == 6) {
      asm volatile("s_waitcnt vmcnt(6)" ::: "memory");  // ts=6 done; 7 in flight
    } else {
      asm volatile("s_waitcnt vmcnt(0)" ::: "memory");  // final tile: drain all
    }
    __builtin_amdgcn_sched_barrier(0);                 // rule #18 fence
    __builtin_amdgcn_s_barrier();                      // all waves' tile ts ready

    half8v ah[2];
#pragma unroll
    for (int mf = 0; mf < 2; ++mf) {
      int row = wave * 32 + mf * 16 + l15;
      int u0 = kb ^ (row & 7);
      int u1 = (kb + 4) ^ (row & 7);
      float4 f0 = *(const float4*)((const char*)Af[cur] + (size_t)row * 128 + u0 * 16);
      float4 f1 = *(const float4*)((const char*)Af[cur] + (size_t)row * 128 + u1 * 16);
      const float e[8] = {f0.x, f0.y, f0.z, f0.w, f1.x, f1.y, f1.z, f1.w};
#pragma unroll
      for (int j = 0; j < 8; ++j) ah[mf][j] = (_Float16)e[j];
    }
#pragma unroll
    for (int nf = 0; nf < 8; ++nf) {
      half8v bh = *(const half8v*)((const char*)Bfs[cur] + (size_t)(nf * 16 + l15) * 64 + kb * 16);
#pragma unroll
      for (int mf = 0; mf < 2; ++mf)
        acc[mf][nf] = __builtin_amdgcn_mfma_f32_16x16x32_f16(ah[mf], bh, acc[mf][nf], 0, 0, 0);
    }
    __builtin_amdgcn_s_barrier();   // readers done before buf reuse (no drain)
  }

  // ---- epilogue: bf16 C (item) + fused scores ----
  if (!isU) {
#pragma unroll
    for (int nf = 0; nf < 8; ++nf) {
      float b8 = bias[nf * 16 + l15];
#pragma unroll
      for (int mf = 0; mf < 2; ++mf) {
#pragma unroll
        for (int r = 0; r < 4; ++r) {
          int grow = m0 + wave * 32 + mf * 16 + kb * 4 + r;
          if (grow < M)
            CiBf[(size_t)grow * D_H + nf * 16 + l15] = f2bf(acc[mf][nf][r] + b8);
        }
      }
    }
  }
  const float* a0 = isU ? aUdst : aUsrc;
  float* s0 = isU ? sUdst : sIsrc;
#pragma unroll
  for (int h = 0; h < HEADS; ++h) {
    float a0v[8], bd0 = 0.f;
#pragma unroll
    for (int nf = 0; nf < 8; ++nf) {
      a0v[nf] = a0[h * D_H + nf * 16 + l15];
      bd0 = fmaf(bias[nf * 16 + l15], a0v[nf], bd0);
    }
#pragma unroll
    for (int mf = 0; mf < 2; ++mf) {
#pragma unroll
      for (int r = 0; r < 4; ++r) {
        float p = bd0;
#pragma unroll
        for (int nf = 0; nf < 8; ++nf) p = fmaf(acc[mf][nf][r], a0v[nf], p);
        p += __shfl_xor(p, 1); p += __shfl_xor(p, 2);
        p += __shfl_xor(p, 4); p += __shfl_xor(p, 8);
        int grow = m0 + wave * 32 + mf * 16 + kb * 4 + r;
        if (l15 == 0 && grow < M) s0[grow * HEADS + h] = p;
      }
    }
  }
  if (!isU) {
#pragma unroll
    for (int h = 0; h < HEADS; ++h) {
      float a1v[8], bd1 = 0.f;
#pragma unroll
      for (int nf = 0; nf < 8; ++nf) {
        a1v[nf] = aIdst[h * D_H + nf * 16 + l15];
        bd1 = fmaf(bias[nf * 16 + l15], a1v[nf], bd1);
      }
#pragma unroll
      for (int mf = 0; mf < 2; ++mf) {
#pragma unroll
        for (int r = 0; r < 4; ++r) {
          float p = bd1;
#pragma unroll
          for (int nf = 0; nf < 8; ++nf) p = fmaf(acc[mf][nf][r], a1v[nf], p);
          p += __shfl_xor(p, 1); p += __shfl_xor(p, 2);
          p += __shfl_xor(p, 4); p += __shfl_xor(p, 8);
          int grow = m0 + wave * 32 + mf * 16 + kb * 4 + r;
          if (l15 == 0 && grow < M) sIdst[grow * HEADS + h] = p;
        }
      }
    }
  }
}

// ---------------------------------------------------------------------------
// Weighted gather-sum with inline edge weights (r18-exact).
// 2 dst/wave, bf16 gather rows; den lane-uniform (no reductions).
// ---------------------------------------------------------------------------
__global__ __launch_bounds__(256) void attend_sum_kernel(
    const unsigned short* __restrict__ h_src, const float* __restrict__ s_src,
    const float* __restrict__ s_dst, const int* __restrict__ src_idx,
    const int* __restrict__ rs, float* __restrict__ out,
    unsigned short* __restrict__ out_bf, int n_dst,
    const float* __restrict__ a_next, float* __restrict__ s_out) {
  int gw = (blockIdx.x * blockDim.x + threadIdx.x) >> 6;   // global wave id
  int lane = threadIdx.x & 63;
  int half = lane >> 5;
  int ll = lane & 31;                // dim group: dims [ll*4, ll*4+4)
  int wid = gw * 2 + half;           // this half's dst node
  if (wid >= n_dst) return;
  int e0 = rs[wid], e1 = rs[wid + 1];
  f32x4 sd = *(const f32x4*)&s_dst[(size_t)wid * HEADS];

#define EDGE_W(sv, wv) {                                                    \
    f32x4 v_ = sv + sd;                                                     \
    v_.x = (v_.x >= 0.f) ? v_.x : 0.2f * v_.x;                              \
    v_.y = (v_.y >= 0.f) ? v_.y : 0.2f * v_.y;                              \
    v_.z = (v_.z >= 0.f) ? v_.z : 0.2f * v_.z;                              \
    v_.w = (v_.w >= 0.f) ? v_.w : 0.2f * v_.w;                              \
    wv = (f32x4){__expf(v_.x), __expf(v_.y), __expf(v_.z), __expf(v_.w)};   \
  }

  f32x4 acc0 = {0, 0, 0, 0}, acc1 = acc0, acc2 = acc0, acc3 = acc0;
  f32x4 den = {0, 0, 0, 0};

  int base = e0;
  for (; base + 2 <= e1; base += 2) {
    int sA = src_idx[base], sB = src_idx[base + 1];
    ushort4 gA = *(const ushort4*)&h_src[(size_t)sA * D_H + ll * 4];
    ushort4 gB = *(const ushort4*)&h_src[(size_t)sB * D_H + ll * 4];
    f32x4 svA = *(const f32x4*)&s_src[(size_t)sA * HEADS];
    f32x4 svB = *(const f32x4*)&s_src[(size_t)sB * HEADS];
    f32x4 hA = {bf2f(gA.x), bf2f(gA.y), bf2f(gA.z), bf2f(gA.w)};
    f32x4 hB = {bf2f(gB.x), bf2f(gB.y), bf2f(gB.z), bf2f(gB.w)};
    f32x4 wA, wB;
    EDGE_W(svA, wA); EDGE_W(svB, wB);
    den += wA; den += wB;
    acc0 = __builtin_elementwise_fma(splat4(wA.x), hA, acc0);
    acc1 = __builtin_elementwise_fma(splat4(wA.y), hA, acc1);
    acc2 = __builtin_elementwise_fma(splat4(wA.z), hA, acc2);
    acc3 = __builtin_elementwise_fma(splat4(wA.w), hA, acc3);
    acc0 = __builtin_elementwise_fma(splat4(wB.x), hB, acc0);
    acc1 = __builtin_elementwise_fma(splat4(wB.y), hB, acc1);
    acc2 = __builtin_elementwise_fma(splat4(wB.z), hB, acc2);
    acc3 = __builtin_elementwise_fma(splat4(wB.w), hB, acc3);
  }
  if (base < e1) {
    int s = src_idx[base];
    ushort4 gv = *(const ushort4*)&h_src[(size_t)s * D_H + ll * 4];
    f32x4 sv = *(const f32x4*)&s_src[(size_t)s * HEADS];
    f32x4 hv = {bf2f(gv.x), bf2f(gv.y), bf2f(gv.z), bf2f(gv.w)};
    f32x4 wv;
    EDGE_W(sv, wv);
    den += wv;
    acc0 = __builtin_elementwise_fma(splat4(wv.x), hv, acc0);
    acc1 = __builtin_elementwise_fma(splat4(wv.y), hv, acc1);
    acc2 = __builtin_elementwise_fma(splat4(wv.z), hv, acc2);
    acc3 = __builtin_elementwise_fma(splat4(wv.w), hv, acc3);
  }
#undef EDGE_W

  float rA = den.x > 0.f ? __builtin_amdgcn_rcpf(den.x) : 0.f;
  float rB = den.y > 0.f ? __builtin_amdgcn_rcpf(den.y) : 0.f;
  float rC = den.z > 0.f ? __builtin_amdgcn_rcpf(den.z) : 0.f;
  float rD = den.w > 0.f ? __builtin_amdgcn_rcpf(den.w) : 0.f;
  acc0 *= splat4(rA); acc1 *= splat4(rB); acc2 *= splat4(rC); acc3 *= splat4(rD);
#define ELU4(a) \
  a.x = (a.x > 0.f) ? a.x : (__expf(a.x) - 1.f); \
  a.y = (a.y > 0.f) ? a.y : (__expf(a.y) - 1.f); \
  a.z = (a.z > 0.f) ? a.z : (__expf(a.z) - 1.f); \
  a.w = (a.w > 0.f) ? a.w : (__expf(a.w) - 1.f);
  ELU4(acc0) ELU4(acc1) ELU4(acc2) ELU4(acc3)
#undef ELU4
  f32x4 o = (acc0 + acc1 + acc2 + acc3) * splat4(0.25f);
  *(f32x4*)&out[(size_t)wid * D_H + ll * 4] = o;
  if (out_bf) {
    ushort4 ob = {f2bf(o.x), f2bf(o.y), f2bf(o.z), f2bf(o.w)};
    *(ushort4*)&out_bf[(size_t)wid * D_H + ll * 4] = ob;
  }

  if (s_out) {
#pragma unroll
    for (int h = 0; h < HEADS; ++h) {
      const float* ah = &a_next[h * D_H + ll * 4];
      float p = o.x * ah[0] + o.y * ah[1] + o.z * ah[2] + o.w * ah[3];
#pragma unroll
      for (int off = 16; off; off >>= 1) p += __shfl_xor(p, off);
      if (ll == 0) s_out[wid * HEADS + h] = p;
    }
  }
}

// ---------------------------------------------------------------------------
extern "C" void kernel_launch(void* const* d_in, const int* in_sizes, int n_in,
                              void* d_out, int out_size, void* d_ws, size_t ws_size,
                              hipStream_t stream) {
  const float* h_user     = (const float*)d_in[0];
  const float* h_item     = (const float*)d_in[1];
  const float* w_user     = (const float*)d_in[2];
  const float* b_user     = (const float*)d_in[3];
  const float* w_item     = (const float*)d_in[4];
  const float* b_item     = (const float*)d_in[5];
  const float* a_user_src = (const float*)d_in[6];
  const float* a_user_dst = (const float*)d_in[7];
  const float* a_item_src = (const float*)d_in[8];
  const float* a_item_dst = (const float*)d_in[9];
  const int* i2u_src = (const int*)d_in[10];
  const int* i2u_dst = (const int*)d_in[11];
  const int* u2i_src = (const int*)d_in[12];
  const int* u2i_dst = (const int*)d_in[13];

  float* out_user = (float*)d_out;                       // hu_new (N_USER,128)
  float* out_item = out_user + (size_t)N_USER * D_H;     // hi_new (N_ITEM,128)

  // workspace layout
  float* base_f  = (float*)d_ws;
  unsigned short* ou_bf = (unsigned short*)base_f;       // (N_USER,128) bf16 25.6MB
  float* s_i_src = (float*)(ou_bf + (size_t)N_USER * D_H);  // (N_ITEM,4)
  float* s_i_dst = s_i_src + (size_t)N_ITEM * HEADS;     // (N_ITEM,4)
  float* s_u_dst = s_i_dst + (size_t)N_ITEM * HEADS;     // (N_USER,4)
  float* s_un    = s_u_dst + (size_t)N_USER * HEADS;     // (N_USER,4)
  int* user_rs = (int*)(s_un + (size_t)N_USER * HEADS);  // N_USER+1
  int* item_rs = user_rs + (N_USER + 1);                 // N_ITEM+1
  _Float16* wtu = (_Float16*)
      (((uintptr_t)(item_rs + N_ITEM + 1) + 15) & ~(uintptr_t)15);
  _Float16* wti = wtu + (size_t)D_IN * D_H;              // 64KB each
  unsigned short* hi_bf = (unsigned short*)(wti + (size_t)D_IN * D_H);  // 12.8MB

  // CSR offsets (edge-parallel run writes)
  hipLaunchKernelGGL(row_offsets_kernel, dim3((N_EDGE + 255) / 256), dim3(256), 0,
                     stream, i2u_dst, N_EDGE, user_rs, N_USER);
  hipLaunchKernelGGL(row_offsets_kernel, dim3((N_EDGE + 255) / 256), dim3(256), 0,
                     stream, u2i_dst, N_EDGE, item_rs, N_ITEM);

  // W prep + FUSED fp16 projections+scores (one dispatch, 1173 blocks)
  hipLaunchKernelGGL(wt_prep_kernel, dim3(D_IN * D_H / 256), dim3(256), 0, stream,
                     w_user, wtu);
  hipLaunchKernelGGL(wt_prep_kernel, dim3(D_IN * D_H / 256), dim3(256), 0, stream,
                     w_item, wti);
  const int nbu = (N_USER + 127) / 128;                  // 782
  const int nbi = (N_ITEM + 127) / 128;                  // 391
  hipLaunchKernelGGL(gemm_fused_kernel, dim3(nbu + nbi), dim3(256), 0, stream,
                     h_user, h_item, wtu, wti, b_user, b_item,
                     a_user_dst, a_user_src, a_item_dst,
                     s_u_dst, s_i_src, s_i_dst, hi_bf, nbu);

  // ---- layer 1: items -> users ----  (bf16 gather; inline edge weights)
  hipLaunchKernelGGL(attend_sum_kernel, dim3((N_USER + 7) / 8), dim3(256), 0, stream,
                     hi_bf, s_i_src, s_u_dst, i2u_src, user_rs,
                     out_user, ou_bf, N_USER, a_item_src, s_un);

  // ---- layer 2: updated users -> items ----
  hipLaunchKernelGGL(attend_sum_kernel, dim3((N_ITEM + 7) / 8), dim3(256), 0, stream,
                     ou_bf, s_un, s_i_dst, u2i_src, item_rs,
                     out_item, (unsigned short*)nullptr, N_ITEM,
                     (const float*)nullptr, (float*)nullptr);
}